// Round 10
// baseline (636.377 us; speedup 1.0000x reference)
//
#include <hip/hip_runtime.h>

#define DEV __device__ __forceinline__

typedef _Float16 f16;
typedef __attribute__((ext_vector_type(8))) _Float16 half8;
typedef __attribute__((ext_vector_type(4))) _Float16 half4;
typedef __attribute__((ext_vector_type(4))) float floatx4;

constexpr int GXc = 480, GYc = 360;
constexpr int NVOX = GXc * GYc;        // 172800
constexpr int BATCH = 2;
constexpr int NPT = 100000;
constexpr int FIN = 7;
constexpr int COUT = 32;
constexpr int MAXPT = 256;
constexpr float EPS = 1e-5f;
constexpr int NBLK = (NVOX + 255) / 256;   // 675
constexpr int FSTRIDE = NPT + 2;           // rowflag per-batch stride
constexpr int NB_PTS = (BATCH * NPT + 255) / 256;  // 782
constexpr int NB_FL  = (NPT + 255) / 256;          // 391
constexpr int ZB = 128;                    // zero-flagged helper blocks

// ---- order-preserving float <-> uint map (for max-as-uint) ----
DEV unsigned f2ord(float f) {
  unsigned b = __float_as_uint(f);
  return (b & 0x80000000u) ? ~b : (b | 0x80000000u);
}
DEV float ord2f(unsigned u) {
  return __uint_as_float((u & 0x80000000u) ? (u & 0x7FFFFFFFu) : ~u);
}

// ---- fused: fold BN0..BN3 into weights (blocks <512) + voxel count (rest) ----
__global__ __launch_bounds__(256)
void k_foldcount(const float* __restrict__ w0, const float* __restrict__ b0,
                 const float* __restrict__ w1, const float* __restrict__ b1,
                 const float* __restrict__ w2, const float* __restrict__ b2,
                 const float* __restrict__ w3, const float* __restrict__ wc,
                 const float* __restrict__ g0, const float* __restrict__ be0, const float* __restrict__ m0, const float* __restrict__ v0,
                 const float* __restrict__ g1, const float* __restrict__ be1, const float* __restrict__ m1, const float* __restrict__ v1,
                 const float* __restrict__ g2, const float* __restrict__ be2, const float* __restrict__ m2, const float* __restrict__ v2,
                 const float* __restrict__ g3, const float* __restrict__ be3, const float* __restrict__ m3, const float* __restrict__ v3,
                 float* __restrict__ A0, float* __restrict__ c0,
                 f16* __restrict__ A1h, float* __restrict__ c1,
                 f16* __restrict__ A2h, float* __restrict__ c2,
                 f16* __restrict__ W3h, f16* __restrict__ Wch,
                 const int* __restrict__ xy, int* __restrict__ vox, int* __restrict__ cnt)
{
  int blk = blockIdx.x;
  if (blk < 512) {
    int id = blk * 256 + threadIdx.x;
    if (id < 131072) W3h[id] = (f16)w3[id];
    if (id < 32768) { int m = id >> 7; A2h[id] = (f16)(w2[id] * (g3[m] * rsqrtf(v3[m] + EPS))); }
    if (id < 16384) Wch[id] = (f16)wc[id];
    if (id < 8192)  { int m = id >> 6; A1h[id] = (f16)(w1[id] * (g2[m] * rsqrtf(v2[m] + EPS))); }
    if (id < 512) {
      int m = id >> 3, k = id & 7;
      A0[id] = (k < 7) ? w0[m * 7 + k] * (g0[k] * rsqrtf(v0[k] + EPS)) * (g1[m] * rsqrtf(v1[m] + EPS)) : 0.f;
    }
    if (id < 64) {
      float t1m = g1[id] * rsqrtf(v1[id] + EPS);
      float a = b0[id];
      for (int k = 0; k < 7; k++) {
        float t0k = g0[k] * rsqrtf(v0[k] + EPS);
        a += (be0[k] - m0[k] * t0k) * w0[id * 7 + k];
      }
      c0[id] = (a - m1[id]) * t1m + be1[id];
    }
    if (id < 128) c1[id] = (b1[id] - m2[id]) * (g2[id] * rsqrtf(v2[id] + EPS)) + be2[id];
    if (id < 256) c2[id] = (b2[id] - m3[id]) * (g3[id] * rsqrtf(v3[id] + EPS)) + be3[id];
  } else {
    int id = (blk - 512) * 256 + threadIdx.x;
    if (id >= BATCH * NPT) return;
    int b = id / NPT;
    int x = xy[id * 2 + 0], y = xy[id * 2 + 1];
    int v = x * GYc + y;
    vox[id] = v;
    atomicAdd(&cnt[b * NVOX + v], 1);
  }
}

// ---- packed scan: hi32 = occupancy prefix (slot), lo32 = count prefix (pofs) ----
__global__ __launch_bounds__(256)
void k_scan1(const int* __restrict__ cnt, int* __restrict__ slot, int* __restrict__ pofs,
             unsigned long long* __restrict__ bsum)
{
  __shared__ unsigned long long sc[256];
  int g = blockIdx.x, tid = threadIdx.x;
  int b = g / NBLK, blk = g % NBLK;
  int v = blk * 256 + tid;
  int c = (v < NVOX) ? cnt[b * NVOX + v] : 0;
  unsigned long long val = ((unsigned long long)(c > 0 ? 1u : 0u) << 32) | (unsigned)c;
  sc[tid] = val;
  __syncthreads();
  for (int off = 1; off < 256; off <<= 1) {
    unsigned long long t = (tid >= off) ? sc[tid - off] : 0ull;
    __syncthreads();
    sc[tid] += t;
    __syncthreads();
  }
  if (v < NVOX) {
    unsigned long long e = sc[tid] - val;   // exclusive
    slot[b * NVOX + v] = (int)(e >> 32);
    pofs[b * NVOX + v] = (int)(unsigned)e;
  }
  if (tid == 255) bsum[g] = sc[255];
}

__global__ __launch_bounds__(256)
void k_scan2(const unsigned long long* __restrict__ bsum, unsigned long long* __restrict__ boff,
             int* __restrict__ Stot)
{
  __shared__ unsigned long long sc[256];
  int b = blockIdx.x, tid = threadIdx.x;
  unsigned long long run = 0;
  for (int i0 = 0; i0 < NBLK; i0 += 256) {
    int i = i0 + tid;
    unsigned long long val = (i < NBLK) ? bsum[b * NBLK + i] : 0ull;
    sc[tid] = val;
    __syncthreads();
    for (int off = 1; off < 256; off <<= 1) {
      unsigned long long t = (tid >= off) ? sc[tid - off] : 0ull;
      __syncthreads();
      sc[tid] += t;
      __syncthreads();
    }
    if (i < NBLK) boff[b * NBLK + i] = run + sc[tid] - val;
    run += sc[255];
    __syncthreads();
  }
  if (tid == 0) Stot[b] = (int)(run >> 32);
}

// ---- finalize scan; mark rows whose group can be atomically updated ----
__global__ __launch_bounds__(256)
void k_scan3(const int* __restrict__ cnt, int* __restrict__ slot, int* __restrict__ pofs,
             const unsigned long long* __restrict__ boff, int* __restrict__ occv,
             int* __restrict__ flag)
{
  int g = blockIdx.x, tid = threadIdx.x;
  int b = g / NBLK, blk = g % NBLK;
  int v = blk * 256 + tid;
  if (v >= NVOX) return;
  unsigned long long bo = boff[g];
  int s = slot[b * NVOX + v] + (int)(bo >> 32);
  int pp = pofs[b * NVOX + v] + (int)(unsigned)bo;
  slot[b * NVOX + v] = s;
  pofs[b * NVOX + v] = pp;
  int c = cnt[b * NVOX + v];
  if (c > 0) {
    occv[b * NPT + s] = v;
    int use = (c > MAXPT) ? MAXPT : c;
    bool capped = (c > MAXPT);
    bool span = ((pp >> 2) != ((pp + use - 1) >> 2));
    if (span || capped) atomicOr(&flag[b * FSTRIDE + s], 1);
    if (capped) atomicOr(&flag[b * FSTRIDE + s + 1], 1);
  }
}

// ---- fused: counting-sort scatter (blocks < NB_PTS) + flag-list compaction ----
__global__ __launch_bounds__(256)
void k_postscan(const int* __restrict__ vox, const int* __restrict__ pofs,
                const int* __restrict__ slot, int* __restrict__ tmp,
                int* __restrict__ order, int* __restrict__ sgrp,
                const int* __restrict__ flag, const int* __restrict__ Stot,
                int* __restrict__ nflag, int* __restrict__ flaglist)
{
  int blk = blockIdx.x;
  if (blk < NB_PTS) {
    int id = blk * 256 + threadIdx.x;
    if (id >= BATCH * NPT) return;
    int b = id / NPT, p = id - b * NPT;
    int v = vox[id];
    int r = atomicAdd(&tmp[b * NVOX + v], 1);
    int pos = pofs[b * NVOX + v] + r;
    order[b * NPT + pos] = p;
    sgrp[b * NPT + pos] = (r < MAXPT) ? slot[b * NVOX + v] : -2;
  } else {
    int rb = blk - NB_PTS;
    int b = rb / NB_FL;
    int s = (rb % NB_FL) * 256 + threadIdx.x;
    if (s >= Stot[b]) return;
    if (flag[b * FSTRIDE + s]) {
      int i = atomicAdd(&nflag[b], 1);
      flaglist[b * NPT + i] = s;
    }
  }
}

// ============ fused L0+L1+L2 per 128-point tile -> H3 (f16) ============
// Trailing ZB blocks (first chunk only) zero the flagged maxf rows instead.
__global__ __launch_bounds__(256)
void k_mlp012(const float* __restrict__ X, const int* __restrict__ order,
              const float* __restrict__ A0, const float* __restrict__ c0,
              const f16* __restrict__ A1h, const float* __restrict__ c1,
              const f16* __restrict__ A2h, const float* __restrict__ c2,
              f16* __restrict__ H3, int P, int nmlp,
              unsigned* __restrict__ maxf, const int* __restrict__ flaglist,
              const int* __restrict__ nflag, int b, int scap)
{
  if (blockIdx.x >= nmlp) {
    int zb = blockIdx.x - nmlp;          // 0..ZB-1
    long long n = (long long)nflag[b] * 128;   // uint4 per row = 128
    uint4 z; z.x = z.y = z.z = z.w = 0u;
    long long stride = (long long)ZB * 256;
    for (long long i = (long long)zb * 256 + threadIdx.x; i < n; i += stride) {
      int s = flaglist[b * NPT + (int)(i >> 7)];
      if (s < scap) ((uint4*)(maxf + (size_t)s * 512))[i & 127] = z;
    }
    return;
  }

  __shared__ __align__(16) char smem[65536];
  f16* H2s = (f16*)smem;                 // [128][128] swizzled
  f16* H1s = (f16*)(smem + 32768);       // [128][64]  swizzled (phases 0-1)
  f16* W1s = (f16*)(smem + 49152);       // [128][64]  swizzled (phases 0-1)
  float* A0s = (float*)smem;             // 512+64 floats, phase 0 only
  float* c0s = A0s + 512;
  f16* W2f = (f16*)(smem + 32768);       // [128][128] swizzled, phase 2 (full mc strip)

  const int tid = threadIdx.x;
  const int p0 = blockIdx.x * 128;
  const int wv = tid >> 6, ln = tid & 63;
  const int wp = (wv & 1) * 64, wm = (wv >> 1) * 64;
  const int l15 = ln & 15, lq = ln >> 4;

  // ---- phase 0 staging: A0/c0 + W1 (swizzled) ----
  A0s[tid] = A0[tid];
  A0s[tid + 256] = A0[tid + 256];
  if (tid < 64) c0s[tid] = c0[tid];
  #pragma unroll
  for (int it = 0; it < 4; it++) {
    int idx = it * 256 + tid;            // half8 index, 1024 total
    int r = idx >> 3, q = idx & 7;
    *(half8*)&W1s[r * 64 + (q ^ (r & 7)) * 8] = *(const half8*)(A1h + r * 64 + q * 8);
  }
  __syncthreads();

  // ---- phase 0 compute: L0, 2 threads per point ----
  {
    int p = tid >> 1, h = tid & 1;
    int pos = p0 + p; if (pos > P - 1) pos = P - 1;
    int pt = order[pos];
    float f[7];
    #pragma unroll
    for (int k = 0; k < 7; k++) f[k] = X[(size_t)pt * 7 + k];
    #pragma unroll
    for (int mm4 = 0; mm4 < 8; mm4++) {
      int mb = h * 32 + mm4 * 4;
      half4 ov;
      #pragma unroll
      for (int j = 0; j < 4; j++) {
        int m = mb + j;
        float a = c0s[m];
        #pragma unroll
        for (int k = 0; k < 7; k++) a += f[k] * A0s[m * 8 + k];
        ov[j] = (f16)(a > 0.f ? a : 0.f);
      }
      *(half4*)&H1s[p * 64 + ((mb >> 3) ^ (p & 7)) * 8 + (mb & 7)] = ov;
    }
  }
  __syncthreads();

  // ---- phase 1: L1 (K=64 -> 128 cols) into H2s ----
  {
    floatx4 acc[4][4];
    #pragma unroll
    for (int i = 0; i < 4; i++)
      #pragma unroll
      for (int j = 0; j < 4; j++) acc[i][j] = (floatx4)0.f;
    #pragma unroll
    for (int k0 = 0; k0 < 64; k0 += 32) {
      half8 af[4], bf[4];
      #pragma unroll
      for (int i = 0; i < 4; i++) {
        int row = wp + i * 16 + l15;
        af[i] = *(const half8*)&H1s[row * 64 + (((k0 >> 3) + lq) ^ (row & 7)) * 8];
      }
      #pragma unroll
      for (int j = 0; j < 4; j++) {
        int row = wm + j * 16 + l15;
        bf[j] = *(const half8*)&W1s[row * 64 + (((k0 >> 3) + lq) ^ (row & 7)) * 8];
      }
      #pragma unroll
      for (int i = 0; i < 4; i++)
        #pragma unroll
        for (int j = 0; j < 4; j++)
          acc[i][j] = __builtin_amdgcn_mfma_f32_16x16x32_f16(af[i], bf[j], acc[i][j], 0, 0, 0);
    }
    float c1j[4];
    #pragma unroll
    for (int j = 0; j < 4; j++) c1j[j] = c1[wm + j * 16 + l15];
    #pragma unroll
    for (int i = 0; i < 4; i++) {
      #pragma unroll
      for (int r = 0; r < 4; r++) {
        int row = wp + i * 16 + lq * 4 + r;
        #pragma unroll
        for (int j = 0; j < 4; j++) {
          int col = wm + j * 16 + l15;
          float v = acc[i][j][r] + c1j[j];
          if (v < 0.f) v = 0.f;
          H2s[row * 128 + ((col >> 3) ^ (row & 7)) * 8 + (col & 7)] = (f16)v;
        }
      }
    }
  }

  // ---- phase 2: L2 (K=128, M=256 in two 128-col chunks) -> H3 global ----
  // Full 32 KB W2 strip staged once per mc into the H1s/W1s region;
  // the 4-iteration K-loop then runs barrier-free on LDS.
  for (int mc = 0; mc < 2; mc++) {
    __syncthreads();   // phase-1 reads done (mc=0) / prev strip reads done (mc=1)
    #pragma unroll
    for (int it = 0; it < 8; it++) {
      int idx = it * 256 + tid;          // 2048 half8 = 128 rows x 16 octs
      int row = idx >> 4, oct = idx & 15;
      *(half8*)&W2f[row * 128 + (oct >> 3) * 64 + ((oct & 7) ^ (row & 7)) * 8] =
          *(const half8*)(A2h + (size_t)(mc * 128 + row) * 128 + oct * 8);
    }
    __syncthreads();

    floatx4 acc[4][4];
    #pragma unroll
    for (int i = 0; i < 4; i++)
      #pragma unroll
      for (int j = 0; j < 4; j++) acc[i][j] = (floatx4)0.f;
    #pragma unroll
    for (int k0 = 0; k0 < 128; k0 += 32) {
      half8 af[4], bf[4];
      #pragma unroll
      for (int i = 0; i < 4; i++) {
        int row = wp + i * 16 + l15;
        af[i] = *(const half8*)&H2s[row * 128 + (((k0 >> 3) + lq) ^ (row & 7)) * 8];
      }
      #pragma unroll
      for (int j = 0; j < 4; j++) {
        int row = wm + j * 16 + l15;
        int oct = (k0 >> 3) + lq;
        bf[j] = *(const half8*)&W2f[row * 128 + (oct >> 3) * 64 + ((oct & 7) ^ (row & 7)) * 8];
      }
      #pragma unroll
      for (int i = 0; i < 4; i++)
        #pragma unroll
        for (int j = 0; j < 4; j++)
          acc[i][j] = __builtin_amdgcn_mfma_f32_16x16x32_f16(af[i], bf[j], acc[i][j], 0, 0, 0);
    }
    float c2j[4];
    #pragma unroll
    for (int j = 0; j < 4; j++) c2j[j] = c2[mc * 128 + wm + j * 16 + l15];
    #pragma unroll
    for (int i = 0; i < 4; i++) {
      #pragma unroll
      for (int r = 0; r < 4; r++) {
        int prow = p0 + wp + i * 16 + lq * 4 + r;
        if (prow < P) {
          #pragma unroll
          for (int j = 0; j < 4; j++) {
            int col = mc * 128 + wm + j * 16 + l15;
            float v = acc[i][j][r] + c2j[j];
            if (v < 0.f) v = 0.f;
            H3[(size_t)prow * 256 + col] = (f16)v;
          }
        }
      }
    }
  }
}

// ---- L3 MFMA GEMM + in-register segmented-max epilogue (K=256, M=512) ----
// R9 K-loop/epilogue verbatim, but one block processes all 4 m-strips of its
// x-tile sequentially: H3 A-tile re-reads hit same-CU L1/L2.
constexpr int LW = 40;

__global__ __launch_bounds__(256)
void k_gemm16_smax(const f16* __restrict__ A, const f16* __restrict__ W,
                   const float* __restrict__ bias, int P,
                   unsigned* __restrict__ maxf, const int* __restrict__ sg,
                   int chunk0, int rest, int scap)
{
  constexpr int K = 256, M = 512;
  __shared__ f16 Xs[128 * LW];
  __shared__ f16 Ws[128 * LW];
  const int tid = threadIdx.x;
  const int p0 = blockIdx.x * 128;
  const int wv = tid >> 6, ln = tid & 63;
  const int wp = (wv & 1) * 64, wm = (wv >> 1) * 64;
  const int l15 = ln & 15, lq = ln >> 4;

  const int sr = tid >> 2, sq = tid & 3;
  int pr = p0 + sr;       if (pr > P - 1) pr = P - 1;
  int pr2 = p0 + sr + 64; if (pr2 > P - 1) pr2 = P - 1;
  const f16* aptr0 = A + (size_t)pr * K + sq * 8;
  const f16* aptr1 = A + (size_t)pr2 * K + sq * 8;

  for (int ms = 0; ms < 4; ms++) {
    const int m0 = ms * 128;
    const f16* wptr0 = W + (size_t)(m0 + sr) * K + sq * 8;
    const f16* wptr1 = W + (size_t)(m0 + sr + 64) * K + sq * 8;

    floatx4 acc[4][4];
    #pragma unroll
    for (int i = 0; i < 4; i++)
      #pragma unroll
      for (int j = 0; j < 4; j++) acc[i][j] = (floatx4)0.f;

    half8 ra0 = *(const half8*)(aptr0);
    half8 ra1 = *(const half8*)(aptr1);
    half8 rw0 = *(const half8*)(wptr0);
    half8 rw1 = *(const half8*)(wptr1);

    #pragma unroll
    for (int k0 = 0; k0 < K; k0 += 32) {
      *(half8*)&Xs[sr * LW + sq * 8]        = ra0;
      *(half8*)&Xs[(sr + 64) * LW + sq * 8] = ra1;
      *(half8*)&Ws[sr * LW + sq * 8]        = rw0;
      *(half8*)&Ws[(sr + 64) * LW + sq * 8] = rw1;
      if (k0 + 32 < K) {                  // prefetch next iteration
        ra0 = *(const half8*)(aptr0 + k0 + 32);
        ra1 = *(const half8*)(aptr1 + k0 + 32);
        rw0 = *(const half8*)(wptr0 + k0 + 32);
        rw1 = *(const half8*)(wptr1 + k0 + 32);
      }
      __syncthreads();
      half8 af[4], bf[4];
      #pragma unroll
      for (int i = 0; i < 4; i++)
        af[i] = *(const half8*)&Xs[(wp + i * 16 + l15) * LW + lq * 8];
      #pragma unroll
      for (int j = 0; j < 4; j++)
        bf[j] = *(const half8*)&Ws[(wm + j * 16 + l15) * LW + lq * 8];
      #pragma unroll
      for (int i = 0; i < 4; i++)
        #pragma unroll
        for (int j = 0; j < 4; j++)
          acc[i][j] = __builtin_amdgcn_mfma_f32_16x16x32_f16(af[i], bf[j], acc[i][j], 0, 0, 0);
      __syncthreads();
    }

    float bj[4];
    #pragma unroll
    for (int j = 0; j < 4; j++) bj[j] = bias[m0 + wm + j * 16 + l15];
    const int cbase = m0 + wm + l15;

    #pragma unroll
    for (int i = 0; i < 4; i++) {
      int pr0 = p0 + wp + i * 16 + lq * 4;
      float run[4];
      int gcur = -1;
      bool openL = false;

      auto flushrun = [&](int gc, bool open) {
        if (gc >= scap) return;
        unsigned* row = maxf + (size_t)gc * M + cbase;
        if (open) {
          #pragma unroll
          for (int j = 0; j < 4; j++) atomicMax(row + j * 16, f2ord(run[j]));
        } else {
          #pragma unroll
          for (int j = 0; j < 4; j++) row[j * 16] = f2ord(run[j]);
        }
      };

      int glast = (chunk0 + pr0 > 0) ? sg[pr0 - 1] : -1;
      #pragma unroll
      for (int r = 0; r < 4; r++) {
        int pos = pr0 + r;
        int g = (pos < P) ? sg[pos] : -1;
        if (g >= 0) {
          if (g == gcur) {
            #pragma unroll
            for (int j = 0; j < 4; j++) run[j] = fmaxf(run[j], acc[i][j][r] + bj[j]);
          } else {
            if (gcur >= 0) flushrun(gcur, openL);
            gcur = g;
            openL = (glast == g) || (glast == -2);
            #pragma unroll
            for (int j = 0; j < 4; j++) run[j] = acc[i][j][r] + bj[j];
          }
        } else {
          if (gcur >= 0) { flushrun(gcur, openL || (g == -2)); gcur = -1; }
        }
        glast = g;
      }
      if (gcur >= 0) {
        int gnext = (pr0 + 4 < rest) ? sg[pr0 + 4] : -1;
        flushrun(gcur, openL || (gnext == gcur) || (gnext == -2));
      }
    }
  }
}

// ---- compression via MFMA: 64-slot x 32-ch tiles; Wc staged once (32 KB,
// swizzled); per-k0 A staging with register prefetch (fp32->f16 in staging).
__global__ __launch_bounds__(256)
void k_compress_mfma(const unsigned* __restrict__ maxf, const f16* __restrict__ Wch,
                     const float* __restrict__ bc, const int* __restrict__ Stot,
                     float* __restrict__ outc, int scap)
{
  int S = Stot[0]; if (S > scap) S = scap;
  const int s0 = blockIdx.x * 64;
  if (s0 >= S) return;
  __shared__ f16 Wcs[32 * 512];   // 32 KB, XOR-swizzled
  __shared__ f16 Xs[64 * LW];     // 5 KB
  const int tid = threadIdx.x;
  const int wv = tid >> 6, ln = tid & 63;
  const int l15 = ln & 15, lq = ln >> 4;

  // stage full Wc once
  #pragma unroll
  for (int it = 0; it < 8; it++) {
    int idx = it * 256 + tid;            // 2048 half8
    int row = idx >> 6, oct = idx & 63;
    *(half8*)&Wcs[row * 512 + (oct >> 3) * 64 + ((oct & 7) ^ (row & 7)) * 8] =
        *(const half8*)(Wch + (size_t)row * 512 + oct * 8);
  }

  // A staging map: idx = l*256+tid -> r = idx>>3 (row 0..63), q = idx&7
  const unsigned* aq[2];
  #pragma unroll
  for (int l = 0; l < 2; l++) {
    int idx = l * 256 + tid;
    int r = idx >> 3, q = idx & 7;
    int srow = s0 + r; if (srow > S - 1) srow = S - 1;
    aq[l] = maxf + (size_t)srow * 512 + q * 4;
  }

  floatx4 acc[2];
  acc[0] = (floatx4)0.f; acc[1] = (floatx4)0.f;

  uint4 pf[2];
  pf[0] = *(const uint4*)(aq[0]);
  pf[1] = *(const uint4*)(aq[1]);

  #pragma unroll
  for (int k0 = 0; k0 < 512; k0 += 32) {
    #pragma unroll
    for (int l = 0; l < 2; l++) {
      int idx = l * 256 + tid;
      int r = idx >> 3, q = idx & 7;
      half4 hv;
      hv[0] = (f16)ord2f(pf[l].x); hv[1] = (f16)ord2f(pf[l].y);
      hv[2] = (f16)ord2f(pf[l].z); hv[3] = (f16)ord2f(pf[l].w);
      *(half4*)&Xs[r * LW + q * 4] = hv;
    }
    if (k0 + 32 < 512) {                 // prefetch next iteration
      pf[0] = *(const uint4*)(aq[0] + k0 + 32);
      pf[1] = *(const uint4*)(aq[1] + k0 + 32);
    }
    __syncthreads();
    half8 af, bf[2];
    af = *(const half8*)&Xs[(wv * 16 + l15) * LW + lq * 8];
    int oct = (k0 >> 3) + lq;
    int hi64 = (oct >> 3) * 64, lo = oct & 7;
    #pragma unroll
    for (int j = 0; j < 2; j++) {
      int row = j * 16 + l15;
      bf[j] = *(const half8*)&Wcs[row * 512 + hi64 + (lo ^ (row & 7)) * 8];
    }
    #pragma unroll
    for (int j = 0; j < 2; j++)
      acc[j] = __builtin_amdgcn_mfma_f32_16x16x32_f16(af, bf[j], acc[j], 0, 0, 0);
    __syncthreads();
  }

  {
    int sb = s0 + wv * 16 + lq * 4;
    #pragma unroll
    for (int r = 0; r < 4; r++) {
      int s = sb + r;
      if (s < S) {
        #pragma unroll
        for (int j = 0; j < 2; j++) {
          int c = j * 16 + l15;
          float v = acc[j][r] + bc[c];
          outc[(size_t)s * COUT + c] = v > 0.f ? v : 0.f;
        }
      }
    }
  }
}

// ---- dense voxel-major output write: out[c][v] = occ ? outc[slot[v]][c] : 0 ----
__global__ __launch_bounds__(256)
void k_scatter_out(const float* __restrict__ outc, const int* __restrict__ cnt,
                   const int* __restrict__ slot, float* __restrict__ outb, int scap)
{
  int v = blockIdx.x * 256 + threadIdx.x;
  if (v >= NVOX) return;
  bool occ = cnt[v] > 0;
  int s = slot[v];
  float4 a[8];
  if (occ && s < scap) {
    #pragma unroll
    for (int q = 0; q < 8; q++) a[q] = *(const float4*)(outc + (size_t)s * COUT + q * 4);
  } else {
    #pragma unroll
    for (int q = 0; q < 8; q++) { a[q].x = 0.f; a[q].y = 0.f; a[q].z = 0.f; a[q].w = 0.f; }
  }
  const float* af = (const float*)a;
  #pragma unroll
  for (int c = 0; c < 32; c++) outb[(size_t)c * NVOX + v] = af[c];
}

extern "C" void kernel_launch(void* const* d_in, const int* in_sizes, int n_in,
                              void* d_out, int out_size, void* d_ws, size_t ws_size,
                              hipStream_t stream) {
  (void)in_sizes; (void)n_in; (void)out_size;
  const float* pt_fea = (const float*)d_in[0];
  const int*   xy     = (const int*)d_in[1];
  const float* w0 = (const float*)d_in[2];  const float* b0 = (const float*)d_in[3];
  const float* w1 = (const float*)d_in[4];  const float* b1 = (const float*)d_in[5];
  const float* w2 = (const float*)d_in[6];  const float* b2 = (const float*)d_in[7];
  const float* w3 = (const float*)d_in[8];  const float* b3 = (const float*)d_in[9];
  const float* g0 = (const float*)d_in[10]; const float* be0 = (const float*)d_in[11];
  const float* m0 = (const float*)d_in[12]; const float* v0  = (const float*)d_in[13];
  const float* g1 = (const float*)d_in[14]; const float* be1 = (const float*)d_in[15];
  const float* m1 = (const float*)d_in[16]; const float* v1  = (const float*)d_in[17];
  const float* g2 = (const float*)d_in[18]; const float* be2 = (const float*)d_in[19];
  const float* m2 = (const float*)d_in[20]; const float* v2  = (const float*)d_in[21];
  const float* g3 = (const float*)d_in[22]; const float* be3 = (const float*)d_in[23];
  const float* m3 = (const float*)d_in[24]; const float* v3  = (const float*)d_in[25];
  const float* wc = (const float*)d_in[26]; const float* bc = (const float*)d_in[27];
  float* outp = (float*)d_out;

  // ---- carve workspace ----
  char* base = (char*)d_ws;
  size_t off = 0;
  auto alloc = [&](size_t n) -> void* {
    void* p = base + off;
    off = (off + n + 255) & ~(size_t)255;
    return p;
  };
  float* A0f = (float*)alloc(512 * 4);    float* c0f = (float*)alloc(64 * 4);
  f16* A1h = (f16*)alloc(8192 * 2);       float* c1f = (float*)alloc(128 * 4);
  f16* A2h = (f16*)alloc(32768 * 2);      float* c2f = (float*)alloc(256 * 4);
  f16* W3h = (f16*)alloc(131072 * 2);
  f16* Wch = (f16*)alloc(16384 * 2);
  int* vox  = (int*)alloc((size_t)BATCH * NPT * 4);
  int* slot = (int*)alloc((size_t)BATCH * NVOX * 4);
  int* pofs = (int*)alloc((size_t)BATCH * NVOX * 4);
  unsigned long long* bsum = (unsigned long long*)alloc((size_t)BATCH * NBLK * 8);
  unsigned long long* boff = (unsigned long long*)alloc((size_t)BATCH * NBLK * 8);
  int* Stot = (int*)alloc((size_t)BATCH * 4);
  int* occv = (int*)alloc((size_t)BATCH * NPT * 4);
  int* order = (int*)alloc((size_t)BATCH * NPT * 4);
  int* sgrp  = (int*)alloc((size_t)BATCH * NPT * 4);
  int* flist = (int*)alloc((size_t)BATCH * NPT * 4);
  float* outc = (float*)alloc((size_t)NPT * COUT * 4);
  // zero region: cnt | tmp | flag | nflag (one memset covers all)
  size_t zoff0 = off;
  int* cnt  = (int*)alloc((size_t)BATCH * NVOX * 4);
  int* tmp  = (int*)alloc((size_t)BATCH * NVOX * 4);
  int* flag = (int*)alloc((size_t)BATCH * FSTRIDE * 4);
  int* nflag = (int*)alloc((size_t)BATCH * 4);
  size_t zlen = off - zoff0;

  // maxf (compact per-slot 512-wide uint max buffer), worst case S = NPT
  int scap = NPT;
  size_t remain = (ws_size > off) ? ws_size - off : 0;
  size_t minH = (size_t)128 * 256 * 2;   // min H3 chunk
  if (remain < (size_t)scap * 512 * 4 + minH) {
    size_t avail = (remain > minH) ? remain - minH : 0;
    scap = (int)(avail / 2048);
    if (scap < 1) scap = 1;
  }
  unsigned* maxf = (unsigned*)alloc((size_t)scap * 512 * 4);

  // chunk size for H3 (f16, 512 B per row)
  size_t hrem = (ws_size > off) ? ws_size - off : 0;
  int P = (int)((hrem / ((size_t)256 * 2)) & ~(size_t)127);
  if (P > NPT) P = ((NPT + 127) / 128) * 128;
  if (P < 128) P = 128;
  f16* H3 = (f16*)alloc((size_t)P * 256 * 2);

  // ---- pipeline ----
  hipMemsetAsync(base + zoff0, 0, zlen, stream);

  k_foldcount<<<512 + NB_PTS, 256, 0, stream>>>(w0, b0, w1, b1, w2, b2, w3, wc,
                                                g0, be0, m0, v0, g1, be1, m1, v1,
                                                g2, be2, m2, v2, g3, be3, m3, v3,
                                                A0f, c0f, A1h, c1f, A2h, c2f, W3h, Wch,
                                                xy, vox, cnt);
  k_scan1<<<BATCH * NBLK, 256, 0, stream>>>(cnt, slot, pofs, bsum);
  k_scan2<<<BATCH, 256, 0, stream>>>(bsum, boff, Stot);
  k_scan3<<<BATCH * NBLK, 256, 0, stream>>>(cnt, slot, pofs, boff, occv, flag);
  k_postscan<<<NB_PTS + BATCH * NB_FL, 256, 0, stream>>>(vox, pofs, slot, tmp, order, sgrp,
                                                         flag, Stot, nflag, flist);

  for (int b = 0; b < BATCH; b++) {
    for (int p0 = 0; p0 < NPT; p0 += P) {
      int pc = (NPT - p0 < P) ? (NPT - p0) : P;
      int nmlp = (pc + 127) / 128;
      int gext = (p0 == 0) ? ZB : 0;     // zero-flagged rides along on first chunk
      k_mlp012<<<nmlp + gext, 256, 0, stream>>>(pt_fea + (size_t)b * NPT * FIN,
                                                order + (size_t)b * NPT + p0,
                                                A0f, c0f, A1h, c1f, A2h, c2f,
                                                H3, pc, nmlp,
                                                maxf, flist, nflag, b, scap);
      k_gemm16_smax<<<nmlp, 256, 0, stream>>>(H3, W3h, b3, pc,
                                              maxf, sgrp + (size_t)b * NPT + p0,
                                              p0, NPT - p0, scap);
    }
    k_compress_mfma<<<(NPT + 63) / 64, 256, 0, stream>>>(maxf, Wch, bc, Stot + b,
                                                         outc, scap);
    k_scatter_out<<<(NVOX + 255) / 256, 256, 0, stream>>>(outc, cnt + (size_t)b * NVOX,
                                                          slot + (size_t)b * NVOX,
                                                          outp + (size_t)b * COUT * NVOX,
                                                          scap);
  }
}

// Round 11
// 564.349 us; speedup vs baseline: 1.1276x; 1.1276x over previous
//
#include <hip/hip_runtime.h>

#define DEV __device__ __forceinline__

typedef _Float16 f16;
typedef __attribute__((ext_vector_type(8))) _Float16 half8;
typedef __attribute__((ext_vector_type(4))) _Float16 half4;
typedef __attribute__((ext_vector_type(4))) float floatx4;

constexpr int GXc = 480, GYc = 360;
constexpr int NVOX = GXc * GYc;        // 172800
constexpr int BATCH = 2;
constexpr int NPT = 100000;
constexpr int FIN = 7;
constexpr int COUT = 32;
constexpr int MAXPT = 256;
constexpr float EPS = 1e-5f;
constexpr int NBLK = (NVOX + 255) / 256;   // 675
constexpr int FSTRIDE = NPT + 2;           // rowflag per-batch stride
constexpr int NB_PTS = (BATCH * NPT + 255) / 256;  // 782
constexpr int NB_FL  = (NPT + 255) / 256;          // 391
constexpr int ZB = 128;                    // zero-flagged helper blocks

// ---- order-preserving float <-> uint map (for max-as-uint) ----
DEV unsigned f2ord(float f) {
  unsigned b = __float_as_uint(f);
  return (b & 0x80000000u) ? ~b : (b | 0x80000000u);
}
DEV float ord2f(unsigned u) {
  return __uint_as_float((u & 0x80000000u) ? (u & 0x7FFFFFFFu) : ~u);
}

// ---- fused: fold BN0..BN3 into weights (blocks <512) + voxel count (rest) ----
__global__ __launch_bounds__(256)
void k_foldcount(const float* __restrict__ w0, const float* __restrict__ b0,
                 const float* __restrict__ w1, const float* __restrict__ b1,
                 const float* __restrict__ w2, const float* __restrict__ b2,
                 const float* __restrict__ w3, const float* __restrict__ wc,
                 const float* __restrict__ g0, const float* __restrict__ be0, const float* __restrict__ m0, const float* __restrict__ v0,
                 const float* __restrict__ g1, const float* __restrict__ be1, const float* __restrict__ m1, const float* __restrict__ v1,
                 const float* __restrict__ g2, const float* __restrict__ be2, const float* __restrict__ m2, const float* __restrict__ v2,
                 const float* __restrict__ g3, const float* __restrict__ be3, const float* __restrict__ m3, const float* __restrict__ v3,
                 float* __restrict__ A0, float* __restrict__ c0,
                 f16* __restrict__ A1h, float* __restrict__ c1,
                 f16* __restrict__ A2h, float* __restrict__ c2,
                 f16* __restrict__ W3h, f16* __restrict__ Wch,
                 const int* __restrict__ xy, int* __restrict__ vox, int* __restrict__ cnt)
{
  int blk = blockIdx.x;
  if (blk < 512) {
    int id = blk * 256 + threadIdx.x;
    if (id < 131072) W3h[id] = (f16)w3[id];
    if (id < 32768) { int m = id >> 7; A2h[id] = (f16)(w2[id] * (g3[m] * rsqrtf(v3[m] + EPS))); }
    if (id < 16384) Wch[id] = (f16)wc[id];
    if (id < 8192)  { int m = id >> 6; A1h[id] = (f16)(w1[id] * (g2[m] * rsqrtf(v2[m] + EPS))); }
    if (id < 512) {
      int m = id >> 3, k = id & 7;
      A0[id] = (k < 7) ? w0[m * 7 + k] * (g0[k] * rsqrtf(v0[k] + EPS)) * (g1[m] * rsqrtf(v1[m] + EPS)) : 0.f;
    }
    if (id < 64) {
      float t1m = g1[id] * rsqrtf(v1[id] + EPS);
      float a = b0[id];
      for (int k = 0; k < 7; k++) {
        float t0k = g0[k] * rsqrtf(v0[k] + EPS);
        a += (be0[k] - m0[k] * t0k) * w0[id * 7 + k];
      }
      c0[id] = (a - m1[id]) * t1m + be1[id];
    }
    if (id < 128) c1[id] = (b1[id] - m2[id]) * (g2[id] * rsqrtf(v2[id] + EPS)) + be2[id];
    if (id < 256) c2[id] = (b2[id] - m3[id]) * (g3[id] * rsqrtf(v3[id] + EPS)) + be3[id];
  } else {
    int id = (blk - 512) * 256 + threadIdx.x;
    if (id >= BATCH * NPT) return;
    int b = id / NPT;
    int x = xy[id * 2 + 0], y = xy[id * 2 + 1];
    int v = x * GYc + y;
    vox[id] = v;
    atomicAdd(&cnt[b * NVOX + v], 1);
  }
}

// ---- packed scan: hi32 = occupancy prefix (slot), lo32 = count prefix (pofs) ----
__global__ __launch_bounds__(256)
void k_scan1(const int* __restrict__ cnt, int* __restrict__ slot, int* __restrict__ pofs,
             unsigned long long* __restrict__ bsum)
{
  __shared__ unsigned long long sc[256];
  int g = blockIdx.x, tid = threadIdx.x;
  int b = g / NBLK, blk = g % NBLK;
  int v = blk * 256 + tid;
  int c = (v < NVOX) ? cnt[b * NVOX + v] : 0;
  unsigned long long val = ((unsigned long long)(c > 0 ? 1u : 0u) << 32) | (unsigned)c;
  sc[tid] = val;
  __syncthreads();
  for (int off = 1; off < 256; off <<= 1) {
    unsigned long long t = (tid >= off) ? sc[tid - off] : 0ull;
    __syncthreads();
    sc[tid] += t;
    __syncthreads();
  }
  if (v < NVOX) {
    unsigned long long e = sc[tid] - val;   // exclusive
    slot[b * NVOX + v] = (int)(e >> 32);
    pofs[b * NVOX + v] = (int)(unsigned)e;
  }
  if (tid == 255) bsum[g] = sc[255];
}

__global__ __launch_bounds__(256)
void k_scan2(const unsigned long long* __restrict__ bsum, unsigned long long* __restrict__ boff,
             int* __restrict__ Stot)
{
  __shared__ unsigned long long sc[256];
  int b = blockIdx.x, tid = threadIdx.x;
  unsigned long long run = 0;
  for (int i0 = 0; i0 < NBLK; i0 += 256) {
    int i = i0 + tid;
    unsigned long long val = (i < NBLK) ? bsum[b * NBLK + i] : 0ull;
    sc[tid] = val;
    __syncthreads();
    for (int off = 1; off < 256; off <<= 1) {
      unsigned long long t = (tid >= off) ? sc[tid - off] : 0ull;
      __syncthreads();
      sc[tid] += t;
      __syncthreads();
    }
    if (i < NBLK) boff[b * NBLK + i] = run + sc[tid] - val;
    run += sc[255];
    __syncthreads();
  }
  if (tid == 0) Stot[b] = (int)(run >> 32);
}

// ---- finalize scan; mark rows whose group can be atomically updated ----
__global__ __launch_bounds__(256)
void k_scan3(const int* __restrict__ cnt, int* __restrict__ slot, int* __restrict__ pofs,
             const unsigned long long* __restrict__ boff, int* __restrict__ occv,
             int* __restrict__ flag)
{
  int g = blockIdx.x, tid = threadIdx.x;
  int b = g / NBLK, blk = g % NBLK;
  int v = blk * 256 + tid;
  if (v >= NVOX) return;
  unsigned long long bo = boff[g];
  int s = slot[b * NVOX + v] + (int)(bo >> 32);
  int pp = pofs[b * NVOX + v] + (int)(unsigned)bo;
  slot[b * NVOX + v] = s;
  pofs[b * NVOX + v] = pp;
  int c = cnt[b * NVOX + v];
  if (c > 0) {
    occv[b * NPT + s] = v;
    int use = (c > MAXPT) ? MAXPT : c;
    bool capped = (c > MAXPT);
    bool span = ((pp >> 2) != ((pp + use - 1) >> 2));
    if (span || capped) atomicOr(&flag[b * FSTRIDE + s], 1);
    if (capped) atomicOr(&flag[b * FSTRIDE + s + 1], 1);
  }
}

// ---- fused: counting-sort scatter (blocks < NB_PTS) + flag-list compaction ----
__global__ __launch_bounds__(256)
void k_postscan(const int* __restrict__ vox, const int* __restrict__ pofs,
                const int* __restrict__ slot, int* __restrict__ tmp,
                int* __restrict__ order, int* __restrict__ sgrp,
                const int* __restrict__ flag, const int* __restrict__ Stot,
                int* __restrict__ nflag, int* __restrict__ flaglist)
{
  int blk = blockIdx.x;
  if (blk < NB_PTS) {
    int id = blk * 256 + threadIdx.x;
    if (id >= BATCH * NPT) return;
    int b = id / NPT, p = id - b * NPT;
    int v = vox[id];
    int r = atomicAdd(&tmp[b * NVOX + v], 1);
    int pos = pofs[b * NVOX + v] + r;
    order[b * NPT + pos] = p;
    sgrp[b * NPT + pos] = (r < MAXPT) ? slot[b * NVOX + v] : -2;
  } else {
    int rb = blk - NB_PTS;
    int b = rb / NB_FL;
    int s = (rb % NB_FL) * 256 + threadIdx.x;
    if (s >= Stot[b]) return;
    if (flag[b * FSTRIDE + s]) {
      int i = atomicAdd(&nflag[b], 1);
      flaglist[b * NPT + i] = s;
    }
  }
}

// ============ fused L0+L1+L2 per 128-point tile -> H3 (f16) ============
// Trailing ZB blocks (first chunk only) zero the flagged maxf rows instead.
__global__ __launch_bounds__(256)
void k_mlp012(const float* __restrict__ X, const int* __restrict__ order,
              const float* __restrict__ A0, const float* __restrict__ c0,
              const f16* __restrict__ A1h, const float* __restrict__ c1,
              const f16* __restrict__ A2h, const float* __restrict__ c2,
              f16* __restrict__ H3, int P, int nmlp,
              unsigned* __restrict__ maxf, const int* __restrict__ flaglist,
              const int* __restrict__ nflag, int b, int scap)
{
  if (blockIdx.x >= nmlp) {
    int zb = blockIdx.x - nmlp;          // 0..ZB-1
    long long n = (long long)nflag[b] * 128;   // uint4 per row = 128
    uint4 z; z.x = z.y = z.z = z.w = 0u;
    long long stride = (long long)ZB * 256;
    for (long long i = (long long)zb * 256 + threadIdx.x; i < n; i += stride) {
      int s = flaglist[b * NPT + (int)(i >> 7)];
      if (s < scap) ((uint4*)(maxf + (size_t)s * 512))[i & 127] = z;
    }
    return;
  }

  __shared__ __align__(16) char smem[65536];
  f16* H2s = (f16*)smem;                 // [128][128] swizzled
  f16* H1s = (f16*)(smem + 32768);       // [128][64]  swizzled
  f16* W1s = (f16*)(smem + 49152);       // [128][64]  swizzled
  float* A0s = (float*)smem;             // 512+64 floats, phase 0 only
  float* c0s = A0s + 512;
  f16* W2s = (f16*)(smem + 32768);       // [128][40] padded, phase 2 only

  const int tid = threadIdx.x;
  const int p0 = blockIdx.x * 128;
  const int wv = tid >> 6, ln = tid & 63;
  const int wp = (wv & 1) * 64, wm = (wv >> 1) * 64;
  const int l15 = ln & 15, lq = ln >> 4;

  // ---- phase 0 staging: A0/c0 + W1 (swizzled) ----
  A0s[tid] = A0[tid];
  A0s[tid + 256] = A0[tid + 256];
  if (tid < 64) c0s[tid] = c0[tid];
  #pragma unroll
  for (int it = 0; it < 4; it++) {
    int idx = it * 256 + tid;            // half8 index, 1024 total
    int r = idx >> 3, q = idx & 7;
    *(half8*)&W1s[r * 64 + (q ^ (r & 7)) * 8] = *(const half8*)(A1h + r * 64 + q * 8);
  }
  __syncthreads();

  // ---- phase 0 compute: L0, 2 threads per point ----
  {
    int p = tid >> 1, h = tid & 1;
    int pos = p0 + p; if (pos > P - 1) pos = P - 1;
    int pt = order[pos];
    float f[7];
    #pragma unroll
    for (int k = 0; k < 7; k++) f[k] = X[(size_t)pt * 7 + k];
    #pragma unroll
    for (int mm4 = 0; mm4 < 8; mm4++) {
      int mb = h * 32 + mm4 * 4;
      half4 ov;
      #pragma unroll
      for (int j = 0; j < 4; j++) {
        int m = mb + j;
        float a = c0s[m];
        #pragma unroll
        for (int k = 0; k < 7; k++) a += f[k] * A0s[m * 8 + k];
        ov[j] = (f16)(a > 0.f ? a : 0.f);
      }
      *(half4*)&H1s[p * 64 + ((mb >> 3) ^ (p & 7)) * 8 + (mb & 7)] = ov;
    }
  }
  __syncthreads();

  // ---- phase 1: L1 (K=64 -> 128 cols) into H2s ----
  {
    floatx4 acc[4][4];
    #pragma unroll
    for (int i = 0; i < 4; i++)
      #pragma unroll
      for (int j = 0; j < 4; j++) acc[i][j] = (floatx4)0.f;
    #pragma unroll
    for (int k0 = 0; k0 < 64; k0 += 32) {
      half8 af[4], bf[4];
      #pragma unroll
      for (int i = 0; i < 4; i++) {
        int row = wp + i * 16 + l15;
        af[i] = *(const half8*)&H1s[row * 64 + (((k0 >> 3) + lq) ^ (row & 7)) * 8];
      }
      #pragma unroll
      for (int j = 0; j < 4; j++) {
        int row = wm + j * 16 + l15;
        bf[j] = *(const half8*)&W1s[row * 64 + (((k0 >> 3) + lq) ^ (row & 7)) * 8];
      }
      #pragma unroll
      for (int i = 0; i < 4; i++)
        #pragma unroll
        for (int j = 0; j < 4; j++)
          acc[i][j] = __builtin_amdgcn_mfma_f32_16x16x32_f16(af[i], bf[j], acc[i][j], 0, 0, 0);
    }
    float c1j[4];
    #pragma unroll
    for (int j = 0; j < 4; j++) c1j[j] = c1[wm + j * 16 + l15];
    #pragma unroll
    for (int i = 0; i < 4; i++) {
      #pragma unroll
      for (int r = 0; r < 4; r++) {
        int row = wp + i * 16 + lq * 4 + r;
        #pragma unroll
        for (int j = 0; j < 4; j++) {
          int col = wm + j * 16 + l15;
          float v = acc[i][j][r] + c1j[j];
          if (v < 0.f) v = 0.f;
          H2s[row * 128 + ((col >> 3) ^ (row & 7)) * 8 + (col & 7)] = (f16)v;
        }
      }
    }
  }
  __syncthreads();

  // ---- phase 2: L2 (K=128, M=256 in two 128-col chunks) -> H3 global ----
  for (int mc = 0; mc < 2; mc++) {
    floatx4 acc[4][4];
    #pragma unroll
    for (int i = 0; i < 4; i++)
      #pragma unroll
      for (int j = 0; j < 4; j++) acc[i][j] = (floatx4)0.f;
    for (int k0 = 0; k0 < 128; k0 += 32) {
      __syncthreads();   // protect W2s overwrite (and H1s on first iter)
      #pragma unroll
      for (int it = 0; it < 2; it++) {
        int idx = it * 256 + tid;        // 512 half8 = 128 rows x 4 q
        int r = idx >> 2, q = idx & 3;
        *(half8*)&W2s[r * 40 + q * 8] =
            *(const half8*)(A2h + (size_t)(mc * 128 + r) * 128 + k0 + q * 8);
      }
      __syncthreads();
      half8 af[4], bf[4];
      #pragma unroll
      for (int i = 0; i < 4; i++) {
        int row = wp + i * 16 + l15;
        af[i] = *(const half8*)&H2s[row * 128 + (((k0 >> 3) + lq) ^ (row & 7)) * 8];
      }
      #pragma unroll
      for (int j = 0; j < 4; j++)
        bf[j] = *(const half8*)&W2s[(wm + j * 16 + l15) * 40 + lq * 8];
      #pragma unroll
      for (int i = 0; i < 4; i++)
        #pragma unroll
        for (int j = 0; j < 4; j++)
          acc[i][j] = __builtin_amdgcn_mfma_f32_16x16x32_f16(af[i], bf[j], acc[i][j], 0, 0, 0);
    }
    float c2j[4];
    #pragma unroll
    for (int j = 0; j < 4; j++) c2j[j] = c2[mc * 128 + wm + j * 16 + l15];
    #pragma unroll
    for (int i = 0; i < 4; i++) {
      #pragma unroll
      for (int r = 0; r < 4; r++) {
        int prow = p0 + wp + i * 16 + lq * 4 + r;
        if (prow < P) {
          #pragma unroll
          for (int j = 0; j < 4; j++) {
            int col = mc * 128 + wm + j * 16 + l15;
            float v = acc[i][j][r] + c2j[j];
            if (v < 0.f) v = 0.f;
            H3[(size_t)prow * 256 + col] = (f16)v;
          }
        }
      }
    }
  }
}

// ---- L3 MFMA GEMM + in-register segmented-max epilogue (K=256, M=512) ----
// R9 K-loop/epilogue verbatim; each block handles 2 m-strips of its x-tile
// (locality/concurrency compromise between R9's 1 and R10's 4). XCD swizzle:
// the two blocks sharing an x-tile are id and id+nxpad (nxpad % 8 == 0) ->
// same XCD -> shared-L2 H3 reuse.
constexpr int LW = 40;

__global__ __launch_bounds__(256)
void k_gemm16_smax(const f16* __restrict__ A, const f16* __restrict__ W,
                   const float* __restrict__ bias, int P,
                   unsigned* __restrict__ maxf, const int* __restrict__ sg,
                   int chunk0, int rest, int scap, int nxpad)
{
  constexpr int K = 256, M = 512;
  __shared__ f16 Xs[128 * LW];
  __shared__ f16 Ws[128 * LW];
  const int tid = threadIdx.x;
  const int xb = blockIdx.x % nxpad;
  const int yb = blockIdx.x / nxpad;     // 0..1, selects strip pair
  if (xb * 128 >= P) return;
  const int p0 = xb * 128;
  const int wv = tid >> 6, ln = tid & 63;
  const int wp = (wv & 1) * 64, wm = (wv >> 1) * 64;
  const int l15 = ln & 15, lq = ln >> 4;

  const int sr = tid >> 2, sq = tid & 3;
  int pr = p0 + sr;       if (pr > P - 1) pr = P - 1;
  int pr2 = p0 + sr + 64; if (pr2 > P - 1) pr2 = P - 1;
  const f16* aptr0 = A + (size_t)pr * K + sq * 8;
  const f16* aptr1 = A + (size_t)pr2 * K + sq * 8;

  for (int ms = 0; ms < 2; ms++) {
    const int m0 = (yb * 2 + ms) * 128;
    const f16* wptr0 = W + (size_t)(m0 + sr) * K + sq * 8;
    const f16* wptr1 = W + (size_t)(m0 + sr + 64) * K + sq * 8;

    floatx4 acc[4][4];
    #pragma unroll
    for (int i = 0; i < 4; i++)
      #pragma unroll
      for (int j = 0; j < 4; j++) acc[i][j] = (floatx4)0.f;

    half8 ra0 = *(const half8*)(aptr0);
    half8 ra1 = *(const half8*)(aptr1);
    half8 rw0 = *(const half8*)(wptr0);
    half8 rw1 = *(const half8*)(wptr1);

    #pragma unroll
    for (int k0 = 0; k0 < K; k0 += 32) {
      *(half8*)&Xs[sr * LW + sq * 8]        = ra0;
      *(half8*)&Xs[(sr + 64) * LW + sq * 8] = ra1;
      *(half8*)&Ws[sr * LW + sq * 8]        = rw0;
      *(half8*)&Ws[(sr + 64) * LW + sq * 8] = rw1;
      if (k0 + 32 < K) {                  // prefetch next iteration
        ra0 = *(const half8*)(aptr0 + k0 + 32);
        ra1 = *(const half8*)(aptr1 + k0 + 32);
        rw0 = *(const half8*)(wptr0 + k0 + 32);
        rw1 = *(const half8*)(wptr1 + k0 + 32);
      }
      __syncthreads();
      half8 af[4], bf[4];
      #pragma unroll
      for (int i = 0; i < 4; i++)
        af[i] = *(const half8*)&Xs[(wp + i * 16 + l15) * LW + lq * 8];
      #pragma unroll
      for (int j = 0; j < 4; j++)
        bf[j] = *(const half8*)&Ws[(wm + j * 16 + l15) * LW + lq * 8];
      #pragma unroll
      for (int i = 0; i < 4; i++)
        #pragma unroll
        for (int j = 0; j < 4; j++)
          acc[i][j] = __builtin_amdgcn_mfma_f32_16x16x32_f16(af[i], bf[j], acc[i][j], 0, 0, 0);
      __syncthreads();
    }

    float bj[4];
    #pragma unroll
    for (int j = 0; j < 4; j++) bj[j] = bias[m0 + wm + j * 16 + l15];
    const int cbase = m0 + wm + l15;

    #pragma unroll
    for (int i = 0; i < 4; i++) {
      int pr0 = p0 + wp + i * 16 + lq * 4;
      float run[4];
      int gcur = -1;
      bool openL = false;

      auto flushrun = [&](int gc, bool open) {
        if (gc >= scap) return;
        unsigned* row = maxf + (size_t)gc * M + cbase;
        if (open) {
          #pragma unroll
          for (int j = 0; j < 4; j++) atomicMax(row + j * 16, f2ord(run[j]));
        } else {
          #pragma unroll
          for (int j = 0; j < 4; j++) row[j * 16] = f2ord(run[j]);
        }
      };

      int glast = (chunk0 + pr0 > 0) ? sg[pr0 - 1] : -1;
      #pragma unroll
      for (int r = 0; r < 4; r++) {
        int pos = pr0 + r;
        int g = (pos < P) ? sg[pos] : -1;
        if (g >= 0) {
          if (g == gcur) {
            #pragma unroll
            for (int j = 0; j < 4; j++) run[j] = fmaxf(run[j], acc[i][j][r] + bj[j]);
          } else {
            if (gcur >= 0) flushrun(gcur, openL);
            gcur = g;
            openL = (glast == g) || (glast == -2);
            #pragma unroll
            for (int j = 0; j < 4; j++) run[j] = acc[i][j][r] + bj[j];
          }
        } else {
          if (gcur >= 0) { flushrun(gcur, openL || (g == -2)); gcur = -1; }
        }
        glast = g;
      }
      if (gcur >= 0) {
        int gnext = (pr0 + 4 < rest) ? sg[pr0 + 4] : -1;
        flushrun(gcur, openL || (gnext == gcur) || (gnext == -2));
      }
    }
  }
}

// ---- compression via MFMA: Wc staged once (swizzled, 32 KB); per-k0 A
// staging with register prefetch. maxf converted fp32->f16 during staging.
__global__ __launch_bounds__(256)
void k_compress_mfma(const unsigned* __restrict__ maxf, const f16* __restrict__ Wch,
                     const float* __restrict__ bc, const int* __restrict__ Stot,
                     float* __restrict__ outc, int scap)
{
  int S = Stot[0]; if (S > scap) S = scap;
  const int s0 = blockIdx.x * 128;
  if (s0 >= S) return;
  __shared__ f16 Wcs[32 * 512];   // 32 KB, XOR-swizzled (R6-proven layout)
  __shared__ f16 Xs[128 * LW];    // 10 KB
  const int tid = threadIdx.x;
  const int wv = tid >> 6, ln = tid & 63;
  const int l15 = ln & 15, lq = ln >> 4;

  // stage full Wc once
  #pragma unroll
  for (int it = 0; it < 8; it++) {
    int idx = it * 256 + tid;            // 2048 half8
    int row = idx >> 6, oct = idx & 63;
    *(half8*)&Wcs[row * 512 + (oct >> 3) * 64 + ((oct & 7) ^ (row & 7)) * 8] =
        *(const half8*)(Wch + (size_t)row * 512 + oct * 8);
  }

  // A staging map: idx = l*256+tid -> r = idx>>3 (row), q = idx&7 (4-f16 quad)
  const unsigned* aq[4];
  #pragma unroll
  for (int l = 0; l < 4; l++) {
    int idx = l * 256 + tid;
    int r = idx >> 3, q = idx & 7;
    int srow = s0 + r; if (srow > S - 1) srow = S - 1;
    aq[l] = maxf + (size_t)srow * 512 + q * 4;
  }

  floatx4 acc[2][2];
  #pragma unroll
  for (int i = 0; i < 2; i++)
    #pragma unroll
    for (int j = 0; j < 2; j++) acc[i][j] = (floatx4)0.f;

  uint4 pf[4];
  #pragma unroll
  for (int l = 0; l < 4; l++) pf[l] = *(const uint4*)(aq[l]);

  #pragma unroll
  for (int k0 = 0; k0 < 512; k0 += 32) {
    #pragma unroll
    for (int l = 0; l < 4; l++) {
      int idx = l * 256 + tid;
      int r = idx >> 3, q = idx & 7;
      half4 hv;
      hv[0] = (f16)ord2f(pf[l].x); hv[1] = (f16)ord2f(pf[l].y);
      hv[2] = (f16)ord2f(pf[l].z); hv[3] = (f16)ord2f(pf[l].w);
      *(half4*)&Xs[r * LW + q * 4] = hv;
    }
    if (k0 + 32 < 512) {                 // prefetch next iteration
      #pragma unroll
      for (int l = 0; l < 4; l++) pf[l] = *(const uint4*)(aq[l] + k0 + 32);
    }
    __syncthreads();
    half8 af[2], bf[2];
    #pragma unroll
    for (int i = 0; i < 2; i++)
      af[i] = *(const half8*)&Xs[(wv * 32 + i * 16 + l15) * LW + lq * 8];
    int oct = (k0 >> 3) + lq;
    int hi64 = (oct >> 3) * 64, lo = oct & 7;
    #pragma unroll
    for (int j = 0; j < 2; j++) {
      int row = j * 16 + l15;
      bf[j] = *(const half8*)&Wcs[row * 512 + hi64 + (lo ^ (row & 7)) * 8];
    }
    #pragma unroll
    for (int i = 0; i < 2; i++)
      #pragma unroll
      for (int j = 0; j < 2; j++)
        acc[i][j] = __builtin_amdgcn_mfma_f32_16x16x32_f16(af[i], bf[j], acc[i][j], 0, 0, 0);
    __syncthreads();
  }

  #pragma unroll
  for (int i = 0; i < 2; i++) {
    int sb = s0 + wv * 32 + i * 16 + lq * 4;
    #pragma unroll
    for (int r = 0; r < 4; r++) {
      int s = sb + r;
      if (s < S) {
        #pragma unroll
        for (int j = 0; j < 2; j++) {
          int c = j * 16 + l15;
          float v = acc[i][j][r] + bc[c];
          outc[(size_t)s * COUT + c] = v > 0.f ? v : 0.f;
        }
      }
    }
  }
}

// ---- dense voxel-major output write: out[c][v] = occ ? outc[slot[v]][c] : 0 ----
__global__ __launch_bounds__(256)
void k_scatter_out(const float* __restrict__ outc, const int* __restrict__ cnt,
                   const int* __restrict__ slot, float* __restrict__ outb, int scap)
{
  int v = blockIdx.x * 256 + threadIdx.x;
  if (v >= NVOX) return;
  bool occ = cnt[v] > 0;
  int s = slot[v];
  float4 a[8];
  if (occ && s < scap) {
    #pragma unroll
    for (int q = 0; q < 8; q++) a[q] = *(const float4*)(outc + (size_t)s * COUT + q * 4);
  } else {
    #pragma unroll
    for (int q = 0; q < 8; q++) { a[q].x = 0.f; a[q].y = 0.f; a[q].z = 0.f; a[q].w = 0.f; }
  }
  const float* af = (const float*)a;
  #pragma unroll
  for (int c = 0; c < 32; c++) outb[(size_t)c * NVOX + v] = af[c];
}

extern "C" void kernel_launch(void* const* d_in, const int* in_sizes, int n_in,
                              void* d_out, int out_size, void* d_ws, size_t ws_size,
                              hipStream_t stream) {
  (void)in_sizes; (void)n_in; (void)out_size;
  const float* pt_fea = (const float*)d_in[0];
  const int*   xy     = (const int*)d_in[1];
  const float* w0 = (const float*)d_in[2];  const float* b0 = (const float*)d_in[3];
  const float* w1 = (const float*)d_in[4];  const float* b1 = (const float*)d_in[5];
  const float* w2 = (const float*)d_in[6];  const float* b2 = (const float*)d_in[7];
  const float* w3 = (const float*)d_in[8];  const float* b3 = (const float*)d_in[9];
  const float* g0 = (const float*)d_in[10]; const float* be0 = (const float*)d_in[11];
  const float* m0 = (const float*)d_in[12]; const float* v0  = (const float*)d_in[13];
  const float* g1 = (const float*)d_in[14]; const float* be1 = (const float*)d_in[15];
  const float* m1 = (const float*)d_in[16]; const float* v1  = (const float*)d_in[17];
  const float* g2 = (const float*)d_in[18]; const float* be2 = (const float*)d_in[19];
  const float* m2 = (const float*)d_in[20]; const float* v2  = (const float*)d_in[21];
  const float* g3 = (const float*)d_in[22]; const float* be3 = (const float*)d_in[23];
  const float* m3 = (const float*)d_in[24]; const float* v3  = (const float*)d_in[25];
  const float* wc = (const float*)d_in[26]; const float* bc = (const float*)d_in[27];
  float* outp = (float*)d_out;

  // ---- carve workspace ----
  char* base = (char*)d_ws;
  size_t off = 0;
  auto alloc = [&](size_t n) -> void* {
    void* p = base + off;
    off = (off + n + 255) & ~(size_t)255;
    return p;
  };
  float* A0f = (float*)alloc(512 * 4);    float* c0f = (float*)alloc(64 * 4);
  f16* A1h = (f16*)alloc(8192 * 2);       float* c1f = (float*)alloc(128 * 4);
  f16* A2h = (f16*)alloc(32768 * 2);      float* c2f = (float*)alloc(256 * 4);
  f16* W3h = (f16*)alloc(131072 * 2);
  f16* Wch = (f16*)alloc(16384 * 2);
  int* vox  = (int*)alloc((size_t)BATCH * NPT * 4);
  int* slot = (int*)alloc((size_t)BATCH * NVOX * 4);
  int* pofs = (int*)alloc((size_t)BATCH * NVOX * 4);
  unsigned long long* bsum = (unsigned long long*)alloc((size_t)BATCH * NBLK * 8);
  unsigned long long* boff = (unsigned long long*)alloc((size_t)BATCH * NBLK * 8);
  int* Stot = (int*)alloc((size_t)BATCH * 4);
  int* occv = (int*)alloc((size_t)BATCH * NPT * 4);
  int* order = (int*)alloc((size_t)BATCH * NPT * 4);
  int* sgrp  = (int*)alloc((size_t)BATCH * NPT * 4);
  int* flist = (int*)alloc((size_t)BATCH * NPT * 4);
  float* outc = (float*)alloc((size_t)NPT * COUT * 4);
  // zero region: cnt | tmp | flag | nflag (one memset covers all)
  size_t zoff0 = off;
  int* cnt  = (int*)alloc((size_t)BATCH * NVOX * 4);
  int* tmp  = (int*)alloc((size_t)BATCH * NVOX * 4);
  int* flag = (int*)alloc((size_t)BATCH * FSTRIDE * 4);
  int* nflag = (int*)alloc((size_t)BATCH * 4);
  size_t zlen = off - zoff0;

  // maxf (compact per-slot 512-wide uint max buffer), worst case S = NPT
  int scap = NPT;
  size_t remain = (ws_size > off) ? ws_size - off : 0;
  size_t minH = (size_t)128 * 256 * 2;   // min H3 chunk
  if (remain < (size_t)scap * 512 * 4 + minH) {
    size_t avail = (remain > minH) ? remain - minH : 0;
    scap = (int)(avail / 2048);
    if (scap < 1) scap = 1;
  }
  unsigned* maxf = (unsigned*)alloc((size_t)scap * 512 * 4);

  // chunk size for H3 (f16, 512 B per row)
  size_t hrem = (ws_size > off) ? ws_size - off : 0;
  int P = (int)((hrem / ((size_t)256 * 2)) & ~(size_t)127);
  if (P > NPT) P = ((NPT + 127) / 128) * 128;
  if (P < 128) P = 128;
  f16* H3 = (f16*)alloc((size_t)P * 256 * 2);

  // ---- pipeline ----
  hipMemsetAsync(base + zoff0, 0, zlen, stream);

  k_foldcount<<<512 + NB_PTS, 256, 0, stream>>>(w0, b0, w1, b1, w2, b2, w3, wc,
                                                g0, be0, m0, v0, g1, be1, m1, v1,
                                                g2, be2, m2, v2, g3, be3, m3, v3,
                                                A0f, c0f, A1h, c1f, A2h, c2f, W3h, Wch,
                                                xy, vox, cnt);
  k_scan1<<<BATCH * NBLK, 256, 0, stream>>>(cnt, slot, pofs, bsum);
  k_scan2<<<BATCH, 256, 0, stream>>>(bsum, boff, Stot);
  k_scan3<<<BATCH * NBLK, 256, 0, stream>>>(cnt, slot, pofs, boff, occv, flag);
  k_postscan<<<NB_PTS + BATCH * NB_FL, 256, 0, stream>>>(vox, pofs, slot, tmp, order, sgrp,
                                                         flag, Stot, nflag, flist);

  for (int b = 0; b < BATCH; b++) {
    for (int p0 = 0; p0 < NPT; p0 += P) {
      int pc = (NPT - p0 < P) ? (NPT - p0) : P;
      int nmlp = (pc + 127) / 128;
      int gext = (p0 == 0) ? ZB : 0;     // zero-flagged rides along on first chunk
      k_mlp012<<<nmlp + gext, 256, 0, stream>>>(pt_fea + (size_t)b * NPT * FIN,
                                                order + (size_t)b * NPT + p0,
                                                A0f, c0f, A1h, c1f, A2h, c2f,
                                                H3, pc, nmlp,
                                                maxf, flist, nflag, b, scap);
      int nxpad = (nmlp + 7) & ~7;       // multiple of 8 -> x-tile pair shares XCD
      k_gemm16_smax<<<nxpad * 2, 256, 0, stream>>>(H3, W3h, b3, pc,
                                                   maxf, sgrp + (size_t)b * NPT + p0,
                                                   p0, NPT - p0, scap, nxpad);
    }
    k_compress_mfma<<<(NPT + 127) / 128, 256, 0, stream>>>(maxf, Wch, bc, Stot + b,
                                                           outc, scap);
    k_scatter_out<<<(NVOX + 255) / 256, 256, 0, stream>>>(outc, cnt + (size_t)b * NVOX,
                                                          slot + (size_t)b * NVOX,
                                                          outp + (size_t)b * COUT * NVOX,
                                                          scap);
  }
}

// Round 12
// 506.373 us; speedup vs baseline: 1.2567x; 1.1145x over previous
//
#include <hip/hip_runtime.h>

#define DEV __device__ __forceinline__

typedef _Float16 f16;
typedef __attribute__((ext_vector_type(8))) _Float16 half8;
typedef __attribute__((ext_vector_type(4))) _Float16 half4;
typedef __attribute__((ext_vector_type(4))) float floatx4;

constexpr int GXc = 480, GYc = 360;
constexpr int NVOX = GXc * GYc;        // 172800
constexpr int BATCH = 2;
constexpr int NPT = 100000;
constexpr int FIN = 7;
constexpr int COUT = 32;
constexpr int MAXPT = 256;
constexpr float EPS = 1e-5f;
constexpr int NBLK = (NVOX + 255) / 256;   // 675
constexpr int FSTRIDE = NPT + 2;           // rowflag per-batch stride
constexpr int NB_PTS = (BATCH * NPT + 255) / 256;  // 782
constexpr int NB_FL  = (NPT + 255) / 256;          // 391
constexpr int ZB = 128;                    // zero-flagged helper blocks

// ---- order-preserving float <-> uint map (for max-as-uint) ----
DEV unsigned f2ord(float f) {
  unsigned b = __float_as_uint(f);
  return (b & 0x80000000u) ? ~b : (b | 0x80000000u);
}
DEV float ord2f(unsigned u) {
  return __uint_as_float((u & 0x80000000u) ? (u & 0x7FFFFFFFu) : ~u);
}

// ---- fused: fold BN0..BN3 into weights (blocks <512) + voxel count (rest) ----
__global__ __launch_bounds__(256)
void k_foldcount(const float* __restrict__ w0, const float* __restrict__ b0,
                 const float* __restrict__ w1, const float* __restrict__ b1,
                 const float* __restrict__ w2, const float* __restrict__ b2,
                 const float* __restrict__ w3, const float* __restrict__ wc,
                 const float* __restrict__ g0, const float* __restrict__ be0, const float* __restrict__ m0, const float* __restrict__ v0,
                 const float* __restrict__ g1, const float* __restrict__ be1, const float* __restrict__ m1, const float* __restrict__ v1,
                 const float* __restrict__ g2, const float* __restrict__ be2, const float* __restrict__ m2, const float* __restrict__ v2,
                 const float* __restrict__ g3, const float* __restrict__ be3, const float* __restrict__ m3, const float* __restrict__ v3,
                 float* __restrict__ A0, float* __restrict__ c0,
                 f16* __restrict__ A1h, float* __restrict__ c1,
                 f16* __restrict__ A2h, float* __restrict__ c2,
                 f16* __restrict__ W3h, f16* __restrict__ Wch,
                 const int* __restrict__ xy, int* __restrict__ vox, int* __restrict__ cnt)
{
  int blk = blockIdx.x;
  if (blk < 512) {
    int id = blk * 256 + threadIdx.x;
    if (id < 131072) W3h[id] = (f16)w3[id];
    if (id < 32768) { int m = id >> 7; A2h[id] = (f16)(w2[id] * (g3[m] * rsqrtf(v3[m] + EPS))); }
    if (id < 16384) Wch[id] = (f16)wc[id];
    if (id < 8192)  { int m = id >> 6; A1h[id] = (f16)(w1[id] * (g2[m] * rsqrtf(v2[m] + EPS))); }
    if (id < 512) {
      int m = id >> 3, k = id & 7;
      A0[id] = (k < 7) ? w0[m * 7 + k] * (g0[k] * rsqrtf(v0[k] + EPS)) * (g1[m] * rsqrtf(v1[m] + EPS)) : 0.f;
    }
    if (id < 64) {
      float t1m = g1[id] * rsqrtf(v1[id] + EPS);
      float a = b0[id];
      for (int k = 0; k < 7; k++) {
        float t0k = g0[k] * rsqrtf(v0[k] + EPS);
        a += (be0[k] - m0[k] * t0k) * w0[id * 7 + k];
      }
      c0[id] = (a - m1[id]) * t1m + be1[id];
    }
    if (id < 128) c1[id] = (b1[id] - m2[id]) * (g2[id] * rsqrtf(v2[id] + EPS)) + be2[id];
    if (id < 256) c2[id] = (b2[id] - m3[id]) * (g3[id] * rsqrtf(v3[id] + EPS)) + be3[id];
  } else {
    int id = (blk - 512) * 256 + threadIdx.x;
    if (id >= BATCH * NPT) return;
    int b = id / NPT;
    int x = xy[id * 2 + 0], y = xy[id * 2 + 1];
    int v = x * GYc + y;
    vox[id] = v;
    atomicAdd(&cnt[b * NVOX + v], 1);
  }
}

// ---- packed scan: hi32 = occupancy prefix (slot), lo32 = count prefix (pofs) ----
__global__ __launch_bounds__(256)
void k_scan1(const int* __restrict__ cnt, int* __restrict__ slot, int* __restrict__ pofs,
             unsigned long long* __restrict__ bsum)
{
  __shared__ unsigned long long sc[256];
  int g = blockIdx.x, tid = threadIdx.x;
  int b = g / NBLK, blk = g % NBLK;
  int v = blk * 256 + tid;
  int c = (v < NVOX) ? cnt[b * NVOX + v] : 0;
  unsigned long long val = ((unsigned long long)(c > 0 ? 1u : 0u) << 32) | (unsigned)c;
  sc[tid] = val;
  __syncthreads();
  for (int off = 1; off < 256; off <<= 1) {
    unsigned long long t = (tid >= off) ? sc[tid - off] : 0ull;
    __syncthreads();
    sc[tid] += t;
    __syncthreads();
  }
  if (v < NVOX) {
    unsigned long long e = sc[tid] - val;   // exclusive
    slot[b * NVOX + v] = (int)(e >> 32);
    pofs[b * NVOX + v] = (int)(unsigned)e;
  }
  if (tid == 255) bsum[g] = sc[255];
}

__global__ __launch_bounds__(256)
void k_scan2(const unsigned long long* __restrict__ bsum, unsigned long long* __restrict__ boff,
             int* __restrict__ Stot)
{
  __shared__ unsigned long long sc[256];
  int b = blockIdx.x, tid = threadIdx.x;
  unsigned long long run = 0;
  for (int i0 = 0; i0 < NBLK; i0 += 256) {
    int i = i0 + tid;
    unsigned long long val = (i < NBLK) ? bsum[b * NBLK + i] : 0ull;
    sc[tid] = val;
    __syncthreads();
    for (int off = 1; off < 256; off <<= 1) {
      unsigned long long t = (tid >= off) ? sc[tid - off] : 0ull;
      __syncthreads();
      sc[tid] += t;
      __syncthreads();
    }
    if (i < NBLK) boff[b * NBLK + i] = run + sc[tid] - val;
    run += sc[255];
    __syncthreads();
  }
  if (tid == 0) Stot[b] = (int)(run >> 32);
}

// ---- finalize scan; mark rows whose group can be atomically updated ----
__global__ __launch_bounds__(256)
void k_scan3(const int* __restrict__ cnt, int* __restrict__ slot, int* __restrict__ pofs,
             const unsigned long long* __restrict__ boff, int* __restrict__ occv,
             int* __restrict__ flag)
{
  int g = blockIdx.x, tid = threadIdx.x;
  int b = g / NBLK, blk = g % NBLK;
  int v = blk * 256 + tid;
  if (v >= NVOX) return;
  unsigned long long bo = boff[g];
  int s = slot[b * NVOX + v] + (int)(bo >> 32);
  int pp = pofs[b * NVOX + v] + (int)(unsigned)bo;
  slot[b * NVOX + v] = s;
  pofs[b * NVOX + v] = pp;
  int c = cnt[b * NVOX + v];
  if (c > 0) {
    occv[b * NPT + s] = v;
    int use = (c > MAXPT) ? MAXPT : c;
    bool capped = (c > MAXPT);
    bool span = ((pp >> 2) != ((pp + use - 1) >> 2));
    if (span || capped) atomicOr(&flag[b * FSTRIDE + s], 1);
    if (capped) atomicOr(&flag[b * FSTRIDE + s + 1], 1);
  }
}

// ---- fused: counting-sort scatter (blocks < NB_PTS) + flag-list compaction ----
__global__ __launch_bounds__(256)
void k_postscan(const int* __restrict__ vox, const int* __restrict__ pofs,
                const int* __restrict__ slot, int* __restrict__ tmp,
                int* __restrict__ order, int* __restrict__ sgrp,
                const int* __restrict__ flag, const int* __restrict__ Stot,
                int* __restrict__ nflag, int* __restrict__ flaglist)
{
  int blk = blockIdx.x;
  if (blk < NB_PTS) {
    int id = blk * 256 + threadIdx.x;
    if (id >= BATCH * NPT) return;
    int b = id / NPT, p = id - b * NPT;
    int v = vox[id];
    int r = atomicAdd(&tmp[b * NVOX + v], 1);
    int pos = pofs[b * NVOX + v] + r;
    order[b * NPT + pos] = p;
    sgrp[b * NPT + pos] = (r < MAXPT) ? slot[b * NVOX + v] : -2;
  } else {
    int rb = blk - NB_PTS;
    int b = rb / NB_FL;
    int s = (rb % NB_FL) * 256 + threadIdx.x;
    if (s >= Stot[b]) return;
    if (flag[b * FSTRIDE + s]) {
      int i = atomicAdd(&nflag[b], 1);
      flaglist[b * NPT + i] = s;
    }
  }
}

// ============ fused L0+L1+L2 per 128-point tile -> H3 (f16) ============
// Trailing ZB blocks (first chunk only) zero the flagged maxf rows instead.
__global__ __launch_bounds__(256)
void k_mlp012(const float* __restrict__ X, const int* __restrict__ order,
              const float* __restrict__ A0, const float* __restrict__ c0,
              const f16* __restrict__ A1h, const float* __restrict__ c1,
              const f16* __restrict__ A2h, const float* __restrict__ c2,
              f16* __restrict__ H3, int P, int nmlp,
              unsigned* __restrict__ maxf, const int* __restrict__ flaglist,
              const int* __restrict__ nflag, int b, int scap)
{
  if (blockIdx.x >= nmlp) {
    int zb = blockIdx.x - nmlp;          // 0..ZB-1
    long long n = (long long)nflag[b] * 128;   // uint4 per row = 128
    uint4 z; z.x = z.y = z.z = z.w = 0u;
    long long stride = (long long)ZB * 256;
    for (long long i = (long long)zb * 256 + threadIdx.x; i < n; i += stride) {
      int s = flaglist[b * NPT + (int)(i >> 7)];
      if (s < scap) ((uint4*)(maxf + (size_t)s * 512))[i & 127] = z;
    }
    return;
  }

  __shared__ __align__(16) char smem[65536];
  f16* H2s = (f16*)smem;                 // [128][128] swizzled
  f16* H1s = (f16*)(smem + 32768);       // [128][64]  swizzled
  f16* W1s = (f16*)(smem + 49152);       // [128][64]  swizzled
  float* A0s = (float*)smem;             // 512+64 floats, phase 0 only
  float* c0s = A0s + 512;
  f16* W2s = (f16*)(smem + 32768);       // [128][40] padded, phase 2 only

  const int tid = threadIdx.x;
  const int p0 = blockIdx.x * 128;
  const int wv = tid >> 6, ln = tid & 63;
  const int wp = (wv & 1) * 64, wm = (wv >> 1) * 64;
  const int l15 = ln & 15, lq = ln >> 4;

  // ---- phase 0 staging: A0/c0 + W1 (swizzled) ----
  A0s[tid] = A0[tid];
  A0s[tid + 256] = A0[tid + 256];
  if (tid < 64) c0s[tid] = c0[tid];
  #pragma unroll
  for (int it = 0; it < 4; it++) {
    int idx = it * 256 + tid;            // half8 index, 1024 total
    int r = idx >> 3, q = idx & 7;
    *(half8*)&W1s[r * 64 + (q ^ (r & 7)) * 8] = *(const half8*)(A1h + r * 64 + q * 8);
  }
  __syncthreads();

  // ---- phase 0 compute: L0, 2 threads per point ----
  {
    int p = tid >> 1, h = tid & 1;
    int pos = p0 + p; if (pos > P - 1) pos = P - 1;
    int pt = order[pos];
    float f[7];
    #pragma unroll
    for (int k = 0; k < 7; k++) f[k] = X[(size_t)pt * 7 + k];
    #pragma unroll
    for (int mm4 = 0; mm4 < 8; mm4++) {
      int mb = h * 32 + mm4 * 4;
      half4 ov;
      #pragma unroll
      for (int j = 0; j < 4; j++) {
        int m = mb + j;
        float a = c0s[m];
        #pragma unroll
        for (int k = 0; k < 7; k++) a += f[k] * A0s[m * 8 + k];
        ov[j] = (f16)(a > 0.f ? a : 0.f);
      }
      *(half4*)&H1s[p * 64 + ((mb >> 3) ^ (p & 7)) * 8 + (mb & 7)] = ov;
    }
  }
  __syncthreads();

  // ---- phase 1: L1 (K=64 -> 128 cols) into H2s ----
  {
    floatx4 acc[4][4];
    #pragma unroll
    for (int i = 0; i < 4; i++)
      #pragma unroll
      for (int j = 0; j < 4; j++) acc[i][j] = (floatx4)0.f;
    #pragma unroll
    for (int k0 = 0; k0 < 64; k0 += 32) {
      half8 af[4], bf[4];
      #pragma unroll
      for (int i = 0; i < 4; i++) {
        int row = wp + i * 16 + l15;
        af[i] = *(const half8*)&H1s[row * 64 + (((k0 >> 3) + lq) ^ (row & 7)) * 8];
      }
      #pragma unroll
      for (int j = 0; j < 4; j++) {
        int row = wm + j * 16 + l15;
        bf[j] = *(const half8*)&W1s[row * 64 + (((k0 >> 3) + lq) ^ (row & 7)) * 8];
      }
      #pragma unroll
      for (int i = 0; i < 4; i++)
        #pragma unroll
        for (int j = 0; j < 4; j++)
          acc[i][j] = __builtin_amdgcn_mfma_f32_16x16x32_f16(af[i], bf[j], acc[i][j], 0, 0, 0);
    }
    float c1j[4];
    #pragma unroll
    for (int j = 0; j < 4; j++) c1j[j] = c1[wm + j * 16 + l15];
    #pragma unroll
    for (int i = 0; i < 4; i++) {
      #pragma unroll
      for (int r = 0; r < 4; r++) {
        int row = wp + i * 16 + lq * 4 + r;
        #pragma unroll
        for (int j = 0; j < 4; j++) {
          int col = wm + j * 16 + l15;
          float v = acc[i][j][r] + c1j[j];
          if (v < 0.f) v = 0.f;
          H2s[row * 128 + ((col >> 3) ^ (row & 7)) * 8 + (col & 7)] = (f16)v;
        }
      }
    }
  }
  __syncthreads();

  // ---- phase 2: L2 (K=128, M=256 in two 128-col chunks) -> H3 global ----
  for (int mc = 0; mc < 2; mc++) {
    floatx4 acc[4][4];
    #pragma unroll
    for (int i = 0; i < 4; i++)
      #pragma unroll
      for (int j = 0; j < 4; j++) acc[i][j] = (floatx4)0.f;
    for (int k0 = 0; k0 < 128; k0 += 32) {
      __syncthreads();   // protect W2s overwrite (and H1s on first iter)
      #pragma unroll
      for (int it = 0; it < 2; it++) {
        int idx = it * 256 + tid;        // 512 half8 = 128 rows x 4 q
        int r = idx >> 2, q = idx & 3;
        *(half8*)&W2s[r * 40 + q * 8] =
            *(const half8*)(A2h + (size_t)(mc * 128 + r) * 128 + k0 + q * 8);
      }
      __syncthreads();
      half8 af[4], bf[4];
      #pragma unroll
      for (int i = 0; i < 4; i++) {
        int row = wp + i * 16 + l15;
        af[i] = *(const half8*)&H2s[row * 128 + (((k0 >> 3) + lq) ^ (row & 7)) * 8];
      }
      #pragma unroll
      for (int j = 0; j < 4; j++)
        bf[j] = *(const half8*)&W2s[(wm + j * 16 + l15) * 40 + lq * 8];
      #pragma unroll
      for (int i = 0; i < 4; i++)
        #pragma unroll
        for (int j = 0; j < 4; j++)
          acc[i][j] = __builtin_amdgcn_mfma_f32_16x16x32_f16(af[i], bf[j], acc[i][j], 0, 0, 0);
    }
    float c2j[4];
    #pragma unroll
    for (int j = 0; j < 4; j++) c2j[j] = c2[mc * 128 + wm + j * 16 + l15];
    #pragma unroll
    for (int i = 0; i < 4; i++) {
      #pragma unroll
      for (int r = 0; r < 4; r++) {
        int prow = p0 + wp + i * 16 + lq * 4 + r;
        if (prow < P) {
          #pragma unroll
          for (int j = 0; j < 4; j++) {
            int col = mc * 128 + wm + j * 16 + l15;
            float v = acc[i][j][r] + c2j[j];
            if (v < 0.f) v = 0.f;
            H3[(size_t)prow * 256 + col] = (f16)v;
          }
        }
      }
    }
  }
}

// ---- L3 MFMA GEMM + in-register segmented-max epilogue (K=256, M=512) ----
// Exact R9 structure (proven 75 us / 530 us total): 1 m-strip per block,
// register-prefetch staging pipeline, XCD swizzle (all 4 strips of one
// x-tile share id%8 -> same XCD). __launch_bounds__ min-waves hint added.
constexpr int LW = 40;

__global__ __launch_bounds__(256, 4)
void k_gemm16_smax(const f16* __restrict__ A, const f16* __restrict__ W,
                   const float* __restrict__ bias, int P,
                   unsigned* __restrict__ maxf, const int* __restrict__ sg,
                   int chunk0, int rest, int scap, int nxpad)
{
  constexpr int K = 256, M = 512;
  __shared__ f16 Xs[128 * LW];
  __shared__ f16 Ws[128 * LW];
  const int tid = threadIdx.x;
  const int xb = blockIdx.x % nxpad;
  const int yb = blockIdx.x / nxpad;
  if (xb * 128 >= P) return;
  const int p0 = xb * 128;
  const int m0 = yb * 128;
  const int wv = tid >> 6, ln = tid & 63;
  const int wp = (wv & 1) * 64, wm = (wv >> 1) * 64;
  const int l15 = ln & 15, lq = ln >> 4;

  floatx4 acc[4][4];
  #pragma unroll
  for (int i = 0; i < 4; i++)
    #pragma unroll
    for (int j = 0; j < 4; j++) acc[i][j] = (floatx4)0.f;

  const int sr = tid >> 2, sq = tid & 3;
  int pr = p0 + sr;       if (pr > P - 1) pr = P - 1;
  int pr2 = p0 + sr + 64; if (pr2 > P - 1) pr2 = P - 1;
  const f16* aptr0 = A + (size_t)pr * K + sq * 8;
  const f16* aptr1 = A + (size_t)pr2 * K + sq * 8;
  const f16* wptr0 = W + (size_t)(m0 + sr) * K + sq * 8;
  const f16* wptr1 = W + (size_t)(m0 + sr + 64) * K + sq * 8;

  half8 ra0 = *(const half8*)(aptr0);
  half8 ra1 = *(const half8*)(aptr1);
  half8 rw0 = *(const half8*)(wptr0);
  half8 rw1 = *(const half8*)(wptr1);

  #pragma unroll
  for (int k0 = 0; k0 < K; k0 += 32) {
    *(half8*)&Xs[sr * LW + sq * 8]        = ra0;
    *(half8*)&Xs[(sr + 64) * LW + sq * 8] = ra1;
    *(half8*)&Ws[sr * LW + sq * 8]        = rw0;
    *(half8*)&Ws[(sr + 64) * LW + sq * 8] = rw1;
    if (k0 + 32 < K) {                    // prefetch next iteration
      ra0 = *(const half8*)(aptr0 + k0 + 32);
      ra1 = *(const half8*)(aptr1 + k0 + 32);
      rw0 = *(const half8*)(wptr0 + k0 + 32);
      rw1 = *(const half8*)(wptr1 + k0 + 32);
    }
    __syncthreads();
    half8 af[4], bf[4];
    #pragma unroll
    for (int i = 0; i < 4; i++)
      af[i] = *(const half8*)&Xs[(wp + i * 16 + l15) * LW + lq * 8];
    #pragma unroll
    for (int j = 0; j < 4; j++)
      bf[j] = *(const half8*)&Ws[(wm + j * 16 + l15) * LW + lq * 8];
    #pragma unroll
    for (int i = 0; i < 4; i++)
      #pragma unroll
      for (int j = 0; j < 4; j++)
        acc[i][j] = __builtin_amdgcn_mfma_f32_16x16x32_f16(af[i], bf[j], acc[i][j], 0, 0, 0);
    __syncthreads();
  }

  float bj[4];
  #pragma unroll
  for (int j = 0; j < 4; j++) bj[j] = bias[m0 + wm + j * 16 + l15];
  const int cbase = m0 + wm + l15;

  #pragma unroll
  for (int i = 0; i < 4; i++) {
    int pr0 = p0 + wp + i * 16 + lq * 4;
    float run[4];
    int gcur = -1;
    bool openL = false;

    auto flushrun = [&](int gc, bool open) {
      if (gc >= scap) return;
      unsigned* row = maxf + (size_t)gc * M + cbase;
      if (open) {
        #pragma unroll
        for (int j = 0; j < 4; j++) atomicMax(row + j * 16, f2ord(run[j]));
      } else {
        #pragma unroll
        for (int j = 0; j < 4; j++) row[j * 16] = f2ord(run[j]);
      }
    };

    int glast = (chunk0 + pr0 > 0) ? sg[pr0 - 1] : -1;
    #pragma unroll
    for (int r = 0; r < 4; r++) {
      int pos = pr0 + r;
      int g = (pos < P) ? sg[pos] : -1;
      if (g >= 0) {
        if (g == gcur) {
          #pragma unroll
          for (int j = 0; j < 4; j++) run[j] = fmaxf(run[j], acc[i][j][r] + bj[j]);
        } else {
          if (gcur >= 0) flushrun(gcur, openL);
          gcur = g;
          openL = (glast == g) || (glast == -2);
          #pragma unroll
          for (int j = 0; j < 4; j++) run[j] = acc[i][j][r] + bj[j];
        }
      } else {
        if (gcur >= 0) { flushrun(gcur, openL || (g == -2)); gcur = -1; }
      }
      glast = g;
    }
    if (gcur >= 0) {
      int gnext = (pr0 + 4 < rest) ? sg[pr0 + 4] : -1;
      flushrun(gcur, openL || (gnext == gcur) || (gnext == -2));
    }
  }
}

// ---- compression via MFMA: Wc staged once (swizzled, 32 KB); per-k0 A
// staging with register prefetch. maxf converted fp32->f16 during staging.
__global__ __launch_bounds__(256)
void k_compress_mfma(const unsigned* __restrict__ maxf, const f16* __restrict__ Wch,
                     const float* __restrict__ bc, const int* __restrict__ Stot,
                     float* __restrict__ outc, int scap)
{
  int S = Stot[0]; if (S > scap) S = scap;
  const int s0 = blockIdx.x * 128;
  if (s0 >= S) return;
  __shared__ f16 Wcs[32 * 512];   // 32 KB, XOR-swizzled (R6-proven layout)
  __shared__ f16 Xs[128 * LW];    // 10 KB
  const int tid = threadIdx.x;
  const int wv = tid >> 6, ln = tid & 63;
  const int l15 = ln & 15, lq = ln >> 4;

  // stage full Wc once
  #pragma unroll
  for (int it = 0; it < 8; it++) {
    int idx = it * 256 + tid;            // 2048 half8
    int row = idx >> 6, oct = idx & 63;
    *(half8*)&Wcs[row * 512 + (oct >> 3) * 64 + ((oct & 7) ^ (row & 7)) * 8] =
        *(const half8*)(Wch + (size_t)row * 512 + oct * 8);
  }

  // A staging map: idx = l*256+tid -> r = idx>>3 (row), q = idx&7 (4-f16 quad)
  const unsigned* aq[4];
  #pragma unroll
  for (int l = 0; l < 4; l++) {
    int idx = l * 256 + tid;
    int r = idx >> 3, q = idx & 7;
    int srow = s0 + r; if (srow > S - 1) srow = S - 1;
    aq[l] = maxf + (size_t)srow * 512 + q * 4;
  }

  floatx4 acc[2][2];
  #pragma unroll
  for (int i = 0; i < 2; i++)
    #pragma unroll
    for (int j = 0; j < 2; j++) acc[i][j] = (floatx4)0.f;

  uint4 pf[4];
  #pragma unroll
  for (int l = 0; l < 4; l++) pf[l] = *(const uint4*)(aq[l]);

  #pragma unroll
  for (int k0 = 0; k0 < 512; k0 += 32) {
    #pragma unroll
    for (int l = 0; l < 4; l++) {
      int idx = l * 256 + tid;
      int r = idx >> 3, q = idx & 7;
      half4 hv;
      hv[0] = (f16)ord2f(pf[l].x); hv[1] = (f16)ord2f(pf[l].y);
      hv[2] = (f16)ord2f(pf[l].z); hv[3] = (f16)ord2f(pf[l].w);
      *(half4*)&Xs[r * LW + q * 4] = hv;
    }
    if (k0 + 32 < 512) {                 // prefetch next iteration
      #pragma unroll
      for (int l = 0; l < 4; l++) pf[l] = *(const uint4*)(aq[l] + k0 + 32);
    }
    __syncthreads();
    half8 af[2], bf[2];
    #pragma unroll
    for (int i = 0; i < 2; i++)
      af[i] = *(const half8*)&Xs[(wv * 32 + i * 16 + l15) * LW + lq * 8];
    int oct = (k0 >> 3) + lq;
    int hi64 = (oct >> 3) * 64, lo = oct & 7;
    #pragma unroll
    for (int j = 0; j < 2; j++) {
      int row = j * 16 + l15;
      bf[j] = *(const half8*)&Wcs[row * 512 + hi64 + (lo ^ (row & 7)) * 8];
    }
    #pragma unroll
    for (int i = 0; i < 2; i++)
      #pragma unroll
      for (int j = 0; j < 2; j++)
        acc[i][j] = __builtin_amdgcn_mfma_f32_16x16x32_f16(af[i], bf[j], acc[i][j], 0, 0, 0);
    __syncthreads();
  }

  #pragma unroll
  for (int i = 0; i < 2; i++) {
    int sb = s0 + wv * 32 + i * 16 + lq * 4;
    #pragma unroll
    for (int r = 0; r < 4; r++) {
      int s = sb + r;
      if (s < S) {
        #pragma unroll
        for (int j = 0; j < 2; j++) {
          int c = j * 16 + l15;
          float v = acc[i][j][r] + bc[c];
          outc[(size_t)s * COUT + c] = v > 0.f ? v : 0.f;
        }
      }
    }
  }
}

// ---- dense voxel-major output write: out[c][v] = occ ? outc[slot[v]][c] : 0 ----
__global__ __launch_bounds__(256)
void k_scatter_out(const float* __restrict__ outc, const int* __restrict__ cnt,
                   const int* __restrict__ slot, float* __restrict__ outb, int scap)
{
  int v = blockIdx.x * 256 + threadIdx.x;
  if (v >= NVOX) return;
  bool occ = cnt[v] > 0;
  int s = slot[v];
  float4 a[8];
  if (occ && s < scap) {
    #pragma unroll
    for (int q = 0; q < 8; q++) a[q] = *(const float4*)(outc + (size_t)s * COUT + q * 4);
  } else {
    #pragma unroll
    for (int q = 0; q < 8; q++) { a[q].x = 0.f; a[q].y = 0.f; a[q].z = 0.f; a[q].w = 0.f; }
  }
  const float* af = (const float*)a;
  #pragma unroll
  for (int c = 0; c < 32; c++) outb[(size_t)c * NVOX + v] = af[c];
}

extern "C" void kernel_launch(void* const* d_in, const int* in_sizes, int n_in,
                              void* d_out, int out_size, void* d_ws, size_t ws_size,
                              hipStream_t stream) {
  (void)in_sizes; (void)n_in; (void)out_size;
  const float* pt_fea = (const float*)d_in[0];
  const int*   xy     = (const int*)d_in[1];
  const float* w0 = (const float*)d_in[2];  const float* b0 = (const float*)d_in[3];
  const float* w1 = (const float*)d_in[4];  const float* b1 = (const float*)d_in[5];
  const float* w2 = (const float*)d_in[6];  const float* b2 = (const float*)d_in[7];
  const float* w3 = (const float*)d_in[8];  const float* b3 = (const float*)d_in[9];
  const float* g0 = (const float*)d_in[10]; const float* be0 = (const float*)d_in[11];
  const float* m0 = (const float*)d_in[12]; const float* v0  = (const float*)d_in[13];
  const float* g1 = (const float*)d_in[14]; const float* be1 = (const float*)d_in[15];
  const float* m1 = (const float*)d_in[16]; const float* v1  = (const float*)d_in[17];
  const float* g2 = (const float*)d_in[18]; const float* be2 = (const float*)d_in[19];
  const float* m2 = (const float*)d_in[20]; const float* v2  = (const float*)d_in[21];
  const float* g3 = (const float*)d_in[22]; const float* be3 = (const float*)d_in[23];
  const float* m3 = (const float*)d_in[24]; const float* v3  = (const float*)d_in[25];
  const float* wc = (const float*)d_in[26]; const float* bc = (const float*)d_in[27];
  float* outp = (float*)d_out;

  // ---- carve workspace ----
  char* base = (char*)d_ws;
  size_t off = 0;
  auto alloc = [&](size_t n) -> void* {
    void* p = base + off;
    off = (off + n + 255) & ~(size_t)255;
    return p;
  };
  float* A0f = (float*)alloc(512 * 4);    float* c0f = (float*)alloc(64 * 4);
  f16* A1h = (f16*)alloc(8192 * 2);       float* c1f = (float*)alloc(128 * 4);
  f16* A2h = (f16*)alloc(32768 * 2);      float* c2f = (float*)alloc(256 * 4);
  f16* W3h = (f16*)alloc(131072 * 2);
  f16* Wch = (f16*)alloc(16384 * 2);
  int* vox  = (int*)alloc((size_t)BATCH * NPT * 4);
  int* slot = (int*)alloc((size_t)BATCH * NVOX * 4);
  int* pofs = (int*)alloc((size_t)BATCH * NVOX * 4);
  unsigned long long* bsum = (unsigned long long*)alloc((size_t)BATCH * NBLK * 8);
  unsigned long long* boff = (unsigned long long*)alloc((size_t)BATCH * NBLK * 8);
  int* Stot = (int*)alloc((size_t)BATCH * 4);
  int* occv = (int*)alloc((size_t)BATCH * NPT * 4);
  int* order = (int*)alloc((size_t)BATCH * NPT * 4);
  int* sgrp  = (int*)alloc((size_t)BATCH * NPT * 4);
  int* flist = (int*)alloc((size_t)BATCH * NPT * 4);
  float* outc = (float*)alloc((size_t)NPT * COUT * 4);
  // zero region: cnt | tmp | flag | nflag (one memset covers all)
  size_t zoff0 = off;
  int* cnt  = (int*)alloc((size_t)BATCH * NVOX * 4);
  int* tmp  = (int*)alloc((size_t)BATCH * NVOX * 4);
  int* flag = (int*)alloc((size_t)BATCH * FSTRIDE * 4);
  int* nflag = (int*)alloc((size_t)BATCH * 4);
  size_t zlen = off - zoff0;

  // maxf (compact per-slot 512-wide uint max buffer), worst case S = NPT
  int scap = NPT;
  size_t remain = (ws_size > off) ? ws_size - off : 0;
  size_t minH = (size_t)128 * 256 * 2;   // min H3 chunk
  if (remain < (size_t)scap * 512 * 4 + minH) {
    size_t avail = (remain > minH) ? remain - minH : 0;
    scap = (int)(avail / 2048);
    if (scap < 1) scap = 1;
  }
  unsigned* maxf = (unsigned*)alloc((size_t)scap * 512 * 4);

  // chunk size for H3 (f16, 512 B per row)
  size_t hrem = (ws_size > off) ? ws_size - off : 0;
  int P = (int)((hrem / ((size_t)256 * 2)) & ~(size_t)127);
  if (P > NPT) P = ((NPT + 127) / 128) * 128;
  if (P < 128) P = 128;
  f16* H3 = (f16*)alloc((size_t)P * 256 * 2);

  // ---- pipeline ----
  hipMemsetAsync(base + zoff0, 0, zlen, stream);

  k_foldcount<<<512 + NB_PTS, 256, 0, stream>>>(w0, b0, w1, b1, w2, b2, w3, wc,
                                                g0, be0, m0, v0, g1, be1, m1, v1,
                                                g2, be2, m2, v2, g3, be3, m3, v3,
                                                A0f, c0f, A1h, c1f, A2h, c2f, W3h, Wch,
                                                xy, vox, cnt);
  k_scan1<<<BATCH * NBLK, 256, 0, stream>>>(cnt, slot, pofs, bsum);
  k_scan2<<<BATCH, 256, 0, stream>>>(bsum, boff, Stot);
  k_scan3<<<BATCH * NBLK, 256, 0, stream>>>(cnt, slot, pofs, boff, occv, flag);
  k_postscan<<<NB_PTS + BATCH * NB_FL, 256, 0, stream>>>(vox, pofs, slot, tmp, order, sgrp,
                                                         flag, Stot, nflag, flist);

  for (int b = 0; b < BATCH; b++) {
    for (int p0 = 0; p0 < NPT; p0 += P) {
      int pc = (NPT - p0 < P) ? (NPT - p0) : P;
      int nmlp = (pc + 127) / 128;
      int gext = (p0 == 0) ? ZB : 0;     // zero-flagged rides along on first chunk
      k_mlp012<<<nmlp + gext, 256, 0, stream>>>(pt_fea + (size_t)b * NPT * FIN,
                                                order + (size_t)b * NPT + p0,
                                                A0f, c0f, A1h, c1f, A2h, c2f,
                                                H3, pc, nmlp,
                                                maxf, flist, nflag, b, scap);
      int nxpad = (nmlp + 7) & ~7;       // multiple of 8 -> same-x strips share XCD
      k_gemm16_smax<<<nxpad * 4, 256, 0, stream>>>(H3, W3h, b3, pc,
                                                   maxf, sgrp + (size_t)b * NPT + p0,
                                                   p0, NPT - p0, scap, nxpad);
    }
    k_compress_mfma<<<(NPT + 127) / 128, 256, 0, stream>>>(maxf, Wch, bc, Stot + b,
                                                           outc, scap);
    k_scatter_out<<<(NVOX + 255) / 256, 256, 0, stream>>>(outc, cnt + (size_t)b * NVOX,
                                                          slot + (size_t)b * NVOX,
                                                          outp + (size_t)b * COUT * NVOX,
                                                          scap);
  }
}